// Round 1
// baseline (1461.335 us; speedup 1.0000x reference)
//
#include <hip/hip_runtime.h>
#include <hip/hip_bf16.h>

#define B_   16
#define L_   2048
#define H_   512
#define NH_  8
#define HH_  64
#define V_   32000
#define T_   32768
#define H2_  1024
#define LM_  2047   // L-1

typedef __attribute__((ext_vector_type(8))) short  short8;
typedef __attribute__((ext_vector_type(4))) float  floatx4;

__device__ inline unsigned short f2b(float x) {
  __hip_bfloat16 h = __float2bfloat16(x);
  return *reinterpret_cast<unsigned short*>(&h);
}

// ---------------------------------------------------------------- prep
// Transpose + bf16-cast weights: W1T[n][k], W2T[n][k], WkvT[j][h] (j = n*64+d for k-heads, 512+n*64+d for v-heads)
__global__ __launch_bounds__(256) void prep_kernel(
    const float* __restrict__ w1, const float* __restrict__ w2,
    const float* __restrict__ wk, const float* __restrict__ wv,
    const float* __restrict__ bk, const float* __restrict__ bv,
    unsigned short* __restrict__ W1T, unsigned short* __restrict__ W2T,
    unsigned short* __restrict__ WkvT, float* __restrict__ bkv)
{
  int id = blockIdx.x * 256 + threadIdx.x;   // 524288 threads
  { // W1T: (1024 x 512) from ff_w1 (512 x 1024)
    int n = id >> 9, k = id & 511;
    W1T[id] = f2b(w1[(size_t)k * H2_ + n]);
  }
  { // W2T: (512 x 1024) from ff_w2 (1024 x 512)
    int n = id >> 10, k = id & 1023;
    W2T[id] = f2b(w2[(size_t)k * H_ + n]);
  }
  { // WkvT: (1024 x 512); wk/wv are (NH, H, HH)
    int j = id >> 9, h = id & 511;
    float val;
    if (j < 512) val = wk[((size_t)(j >> 6) * H_ + h) * HH_ + (j & 63)];
    else { int jj = j - 512; val = wv[((size_t)(jj >> 6) * H_ + h) * HH_ + (jj & 63)]; }
    WkvT[id] = f2b(val);
  }
  if (id < 1024) bkv[id] = (id < 512) ? bk[id] : bv[id - 512];
}

// ---------------------------------------------------------------- gather
// E[t][h] = bf16(embed[seq[t]][h]); one wave per token
__global__ __launch_bounds__(256) void gather_kernel(
    const int* __restrict__ seq, const float* __restrict__ embed,
    unsigned short* __restrict__ E)
{
  int t = blockIdx.x * 4 + (threadIdx.x >> 6);
  int lane = threadIdx.x & 63;
  const float* er = embed + (size_t)seq[t] * H_;
  float4 a = *(const float4*)(er + lane * 8);
  float4 b = *(const float4*)(er + lane * 8 + 4);
  uint4 o;
  o.x = (unsigned)f2b(a.x) | ((unsigned)f2b(a.y) << 16);
  o.y = (unsigned)f2b(a.z) | ((unsigned)f2b(a.w) << 16);
  o.z = (unsigned)f2b(b.x) | ((unsigned)f2b(b.y) << 16);
  o.w = (unsigned)f2b(b.z) | ((unsigned)f2b(b.w) << 16);
  *(uint4*)(E + (size_t)t * H_ + lane * 8) = o;
}

// ---------------------------------------------------------------- GEMM
// C[M][N] = A[M][K] @ BT[N][K]^T + bias, 128x128 tile, BK=64, 4 waves.
// EPI 0: relu -> bf16 store (stride NDIM)
// EPI 1: f32 store (stride NDIM)
// EPI 2: f32 store remapped to KV[(l*16+b)*1024 + col], skip l==2047
template<int KDIM, int NDIM, int EPI>
__global__ __launch_bounds__(256) void gemm_bt(
    const unsigned short* __restrict__ A, const unsigned short* __restrict__ BT,
    const float* __restrict__ bias, void* __restrict__ outp)
{
  __shared__ uint4 smv[2048];                 // 32 KiB: As 16K + Bs 16K
  char* As = (char*)smv;
  char* Bs = As + 16384;
  const int tid = threadIdx.x;
  const int t0 = blockIdx.x * 128;
  const int n0 = blockIdx.y * 128;
  const int wid = tid >> 6, lane = tid & 63;
  const int wm = wid >> 1, wn = wid & 1;
  const int lhi = lane >> 4, llo = lane & 15;

  floatx4 acc[4][4];
  #pragma unroll
  for (int m = 0; m < 4; ++m)
    #pragma unroll
    for (int n = 0; n < 4; ++n)
      acc[m][n] = (floatx4){0.f, 0.f, 0.f, 0.f};

  for (int k0 = 0; k0 < KDIM; k0 += 64) {
    #pragma unroll
    for (int i = 0; i < 4; ++i) {            // stage 128x64 bf16 for A and B
      int idx = tid + i * 256;               // 0..1023 16B-chunks
      int row = idx >> 3, c = idx & 7;
      uint4 va = *(const uint4*)(A  + (size_t)(t0 + row) * KDIM + k0 + c * 8);
      uint4 vb = *(const uint4*)(BT + (size_t)(n0 + row) * KDIM + k0 + c * 8);
      int off = row * 128 + ((c * 16) ^ ((row & 7) << 4));   // XOR swizzle (G4)
      *(uint4*)(As + off) = va;
      *(uint4*)(Bs + off) = vb;
    }
    __syncthreads();
    #pragma unroll
    for (int kk = 0; kk < 2; ++kk) {
      short8 af[4], bfr[4];
      #pragma unroll
      for (int s = 0; s < 4; ++s) {
        int arow = wm * 64 + s * 16 + llo;
        af[s]  = *(const short8*)(As + arow * 128 + ((kk * 64 + lhi * 16) ^ ((arow & 7) << 4)));
        int brow = wn * 64 + s * 16 + llo;
        bfr[s] = *(const short8*)(Bs + brow * 128 + ((kk * 64 + lhi * 16) ^ ((brow & 7) << 4)));
      }
      #pragma unroll
      for (int m = 0; m < 4; ++m)
        #pragma unroll
        for (int n = 0; n < 4; ++n)
          acc[m][n] = __builtin_amdgcn_mfma_f32_16x16x32_bf16(af[m], bfr[n], acc[m][n], 0, 0, 0);
    }
    __syncthreads();
  }

  #pragma unroll
  for (int m = 0; m < 4; ++m) {
    int grow0 = t0 + wm * 64 + m * 16 + lhi * 4;   // C/D: row=(lane>>4)*4+r, col=lane&15
    #pragma unroll
    for (int n = 0; n < 4; ++n) {
      int gcol = n0 + wn * 64 + n * 16 + llo;
      float bb = bias[gcol];
      #pragma unroll
      for (int r = 0; r < 4; ++r) {
        int grow = grow0 + r;
        float v = acc[m][n][r] + bb;
        if (EPI == 0) {
          v = fmaxf(v, 0.f);
          ((unsigned short*)outp)[(size_t)grow * NDIM + gcol] = f2b(v);
        } else if (EPI == 1) {
          ((float*)outp)[(size_t)grow * NDIM + gcol] = v;
        } else {
          int l = grow & (L_ - 1), b = grow >> 11;
          if (l != LM_)
            ((float*)outp)[((size_t)(l * B_ + b)) * H2_ + gcol] = v;
        }
      }
    }
  }
}

// ---------------------------------------------------------------- LN
// x = X[t] + embed[seq[t]]; h = (x-mu)*rsqrt(var+1e-5)*g + b -> bf16; last token per batch also f32
__global__ __launch_bounds__(256) void ln_kernel(
    const float* __restrict__ X, const int* __restrict__ seq,
    const float* __restrict__ embed, const float* __restrict__ gam,
    const float* __restrict__ bet, unsigned short* __restrict__ Hbf,
    float* __restrict__ Hlast)
{
  int t = blockIdx.x * 4 + (threadIdx.x >> 6);
  int lane = threadIdx.x & 63;
  const float* xr = X + (size_t)t * H_;
  const float* er = embed + (size_t)seq[t] * H_;
  float4 x0 = *(const float4*)(xr + lane * 8);
  float4 x1 = *(const float4*)(xr + lane * 8 + 4);
  float4 e0 = *(const float4*)(er + lane * 8);
  float4 e1 = *(const float4*)(er + lane * 8 + 4);
  float xs[8] = {x0.x + e0.x, x0.y + e0.y, x0.z + e0.z, x0.w + e0.w,
                 x1.x + e1.x, x1.y + e1.y, x1.z + e1.z, x1.w + e1.w};
  float sum = 0.f, sq = 0.f;
  #pragma unroll
  for (int j = 0; j < 8; ++j) { sum += xs[j]; sq = fmaf(xs[j], xs[j], sq); }
  #pragma unroll
  for (int m = 1; m < 64; m <<= 1) { sum += __shfl_xor(sum, m); sq += __shfl_xor(sq, m); }
  float mu = sum * (1.f / H_);
  float var = sq * (1.f / H_) - mu * mu;
  float rs = rsqrtf(var + 1e-5f);
  float4 g0 = *(const float4*)(gam + lane * 8);
  float4 g1 = *(const float4*)(gam + lane * 8 + 4);
  float4 b0 = *(const float4*)(bet + lane * 8);
  float4 b1 = *(const float4*)(bet + lane * 8 + 4);
  float gs[8] = {g0.x, g0.y, g0.z, g0.w, g1.x, g1.y, g1.z, g1.w};
  float bs[8] = {b0.x, b0.y, b0.z, b0.w, b1.x, b1.y, b1.z, b1.w};
  float h[8];
  #pragma unroll
  for (int j = 0; j < 8; ++j) h[j] = (xs[j] - mu) * rs * gs[j] + bs[j];
  uint4 o;
  o.x = (unsigned)f2b(h[0]) | ((unsigned)f2b(h[1]) << 16);
  o.y = (unsigned)f2b(h[2]) | ((unsigned)f2b(h[3]) << 16);
  o.z = (unsigned)f2b(h[4]) | ((unsigned)f2b(h[5]) << 16);
  o.w = (unsigned)f2b(h[6]) | ((unsigned)f2b(h[7]) << 16);
  *(uint4*)(Hbf + (size_t)t * H_ + lane * 8) = o;
  if ((t & (L_ - 1)) == LM_) {
    int bi = t >> 11;
    #pragma unroll
    for (int j = 0; j < 8; ++j) Hlast[bi * H_ + lane * 8 + j] = h[j];
  }
}

// ---------------------------------------------------------------- q projection (fp32, exact path)
__global__ __launch_bounds__(64) void qproj_kernel(
    const float* __restrict__ Hlast, const float* __restrict__ wq,
    const float* __restrict__ bq, float* __restrict__ qbuf)
{
  int b = blockIdx.x >> 3, n = blockIdx.x & 7;
  int d = threadIdx.x;
  float acc = bq[n * 64 + d];
  const float* w = wq + (size_t)n * H_ * HH_ + d;
  const float* h = Hlast + b * H_;
  for (int k = 0; k < H_; ++k) acc = fmaf(h[k], w[(size_t)k * HH_], acc);
  qbuf[b * H_ + n * 64 + d] = acc;
}

// ---------------------------------------------------------------- scan (delta rule), fp32
// 512 blocks of 1 wave; block = (b,n,rowgroup of 16 rows). Thread (il,g): rows i=rg*16+il, cols g*16..g*16+15.
__device__ inline void load_kv(const float* __restrict__ base, int l, int g, int i,
                               float (&kr)[16], float& vi) {
  const float* p = base + (size_t)l * (B_ * H2_) + g * 16;
  float4 a = *(const float4*)(p);
  float4 b = *(const float4*)(p + 4);
  float4 c = *(const float4*)(p + 8);
  float4 d = *(const float4*)(p + 12);
  kr[0]=a.x; kr[1]=a.y; kr[2]=a.z; kr[3]=a.w;
  kr[4]=b.x; kr[5]=b.y; kr[6]=b.z; kr[7]=b.w;
  kr[8]=c.x; kr[9]=c.y; kr[10]=c.z; kr[11]=c.w;
  kr[12]=d.x; kr[13]=d.y; kr[14]=d.z; kr[15]=d.w;
  vi = base[(size_t)l * (B_ * H2_) + 512 + i];
}

__device__ inline void delta_step(float (&M)[16], const float (&kr)[16], float vi) {
  float p0=0,p1=0,p2=0,p3=0, s0=0,s1=0,s2=0,s3=0;
  #pragma unroll
  for (int c = 0; c < 4; ++c) {
    p0 = fmaf(M[c],    kr[c],    p0);
    p1 = fmaf(M[c+4],  kr[c+4],  p1);
    p2 = fmaf(M[c+8],  kr[c+8],  p2);
    p3 = fmaf(M[c+12], kr[c+12], p3);
    s0 = fmaf(kr[c],    kr[c],    s0);
    s1 = fmaf(kr[c+4],  kr[c+4],  s1);
    s2 = fmaf(kr[c+8],  kr[c+8],  s2);
    s3 = fmaf(kr[c+12], kr[c+12], s3);
  }
  float p = (p0 + p1) + (p2 + p3);
  float s = (s0 + s1) + (s2 + s3);
  p += __shfl_xor(p, 1); p += __shfl_xor(p, 2);
  s += __shfl_xor(s, 1); s += __shfl_xor(s, 2);
  float d = vi - p / (s + 1e-6f);
  #pragma unroll
  for (int c = 0; c < 16; ++c) M[c] = fmaf(d, kr[c], M[c]);
}

__global__ __launch_bounds__(64) void scan_kernel(
    const float* __restrict__ KV, const float* __restrict__ qbuf,
    float* __restrict__ ctx)
{
  int pair = blockIdx.x >> 2, rg = blockIdx.x & 3;
  int b = pair >> 3, n = pair & 7;
  int lane = threadIdx.x;
  int il = lane >> 2, g = lane & 3;
  int i = rg * 16 + il;
  const float* base = KV + (size_t)b * H2_ + n * 64;
  float M[16];
  #pragma unroll
  for (int c = 0; c < 16; ++c) M[c] = 0.f;
  float ka[16], va_, kb[16], vb_;
  load_kv(base, 0, g, i, ka, va_);
  for (int l = 0; l < LM_; l += 2) {
    if (l + 1 < LM_) load_kv(base, l + 1, g, i, kb, vb_);
    delta_step(M, ka, va_);
    if (l + 1 >= LM_) break;
    if (l + 2 < LM_) load_kv(base, l + 2, g, i, ka, va_);
    delta_step(M, kb, vb_);
  }
  // ctx[b][n*64+i] = sum_j M[i][j] q[j]
  const float* qp = qbuf + b * H_ + n * 64 + g * 16;
  float4 qa = *(const float4*)(qp);
  float4 qb = *(const float4*)(qp + 4);
  float4 qc = *(const float4*)(qp + 8);
  float4 qd = *(const float4*)(qp + 12);
  float q[16] = {qa.x,qa.y,qa.z,qa.w, qb.x,qb.y,qb.z,qb.w,
                 qc.x,qc.y,qc.z,qc.w, qd.x,qd.y,qd.z,qd.w};
  float p = 0.f;
  #pragma unroll
  for (int c = 0; c < 16; ++c) p = fmaf(M[c], q[c], p);
  p += __shfl_xor(p, 1); p += __shfl_xor(p, 2);
  if (g == 0) ctx[b * H_ + n * 64 + i] = p;
}

// ---------------------------------------------------------------- output projections (fp32)
__global__ __launch_bounds__(256) void opproj_kernel(
    const float* __restrict__ ctx, const float* __restrict__ wop,
    const float* __restrict__ bop, float* __restrict__ o1t)
{
  int id = blockIdx.x * 256 + threadIdx.x;   // 8192
  int b = id >> 9, h = id & 511;
  float acc = bop[h];
  const float* c = ctx + b * H_;
  for (int k = 0; k < H_; ++k) acc = fmaf(c[k], wop[(size_t)k * H_ + h], acc);
  o1t[h * B_ + b] = acc;                     // [h][b] for vectorized reads downstream
}

__global__ __launch_bounds__(256) void outproj_kernel(
    const float* __restrict__ o1t, const float* __restrict__ wout,
    const float* __restrict__ bout, float* __restrict__ out)
{
  __shared__ float o1s[H_ * B_];             // 32 KiB
  for (int idx = threadIdx.x; idx < H_ * B_; idx += 256) o1s[idx] = o1t[idx];
  __syncthreads();
  int v = blockIdx.x * 256 + threadIdx.x;    // 125 blocks * 256 = 32000 exactly
  float bo = bout[v];
  float acc[B_];
  #pragma unroll
  for (int b = 0; b < B_; ++b) acc[b] = bo;
  for (int h = 0; h < H_; ++h) {
    float w = wout[(size_t)h * V_ + v];
    const float4* op = (const float4*)&o1s[h * B_];
    float4 a0 = op[0], a1 = op[1], a2 = op[2], a3 = op[3];
    float oa[16] = {a0.x,a0.y,a0.z,a0.w, a1.x,a1.y,a1.z,a1.w,
                    a2.x,a2.y,a2.z,a2.w, a3.x,a3.y,a3.z,a3.w};
    #pragma unroll
    for (int b = 0; b < B_; ++b) acc[b] = fmaf(oa[b], w, acc[b]);
  }
  #pragma unroll
  for (int b = 0; b < B_; ++b) out[(size_t)b * V_ + v] = acc[b];
}

// ---------------------------------------------------------------- launch
extern "C" void kernel_launch(void* const* d_in, const int* in_sizes, int n_in,
                              void* d_out, int out_size, void* d_ws, size_t ws_size,
                              hipStream_t stream)
{
  const int*   seq   = (const int*)d_in[0];
  const float* embed = (const float*)d_in[1];
  const float* ffw1  = (const float*)d_in[2];
  const float* ffb1  = (const float*)d_in[3];
  const float* ffw2  = (const float*)d_in[4];
  const float* ffb2  = (const float*)d_in[5];
  const float* lng   = (const float*)d_in[6];
  const float* lnb   = (const float*)d_in[7];
  const float* wk    = (const float*)d_in[8];
  const float* bk    = (const float*)d_in[9];
  const float* wv    = (const float*)d_in[10];
  const float* bv    = (const float*)d_in[11];
  const float* wq    = (const float*)d_in[12];
  const float* bq    = (const float*)d_in[13];
  const float* wop   = (const float*)d_in[14];
  const float* bop   = (const float*)d_in[15];
  const float* wout  = (const float*)d_in[16];
  const float* bout  = (const float*)d_in[17];

  char* ws = (char*)d_ws;
  const size_t MB = 1024 * 1024;
  unsigned short* W1T   = (unsigned short*)(ws + 0 * MB);   // 1 MB
  unsigned short* W2T   = (unsigned short*)(ws + 1 * MB);   // 1 MB
  unsigned short* WkvT  = (unsigned short*)(ws + 2 * MB);   // 1 MB
  float*          bkv   = (float*)(ws + 3 * MB);            // 4 KB
  float*          Hlast = (float*)(ws + 3 * MB + 8192);     // 32 KB
  float*          qbuf  = (float*)(ws + 3 * MB + 8192 + 32768);
  float*          ctx   = (float*)(ws + 3 * MB + 8192 + 2 * 32768);
  float*          o1t   = (float*)(ws + 3 * MB + 8192 + 3 * 32768);
  unsigned short* E     = (unsigned short*)(ws + 4 * MB);   // 32 MB  [4,36)
  unsigned short* Hbf   = E;                                // reuses E after FFN consumes it
  unsigned short* Hmid  = (unsigned short*)(ws + 36 * MB);  // 64 MB  [36,100)
  float*          X     = (float*)(ws + 100 * MB);          // 64 MB  [100,164)
  float*          KV    = (float*)(ws + 36 * MB);           // 128 MB [36,164) reuses Hmid+X after LN

  prep_kernel  <<<dim3(2048), dim3(256), 0, stream>>>(ffw1, ffw2, wk, wv, bk, bv, W1T, W2T, WkvT, bkv);
  gather_kernel<<<dim3(8192), dim3(256), 0, stream>>>(seq, embed, E);
  gemm_bt<512, 1024, 0><<<dim3(256, 8), dim3(256), 0, stream>>>(E, W1T, ffb1, Hmid);
  gemm_bt<1024, 512, 1><<<dim3(256, 4), dim3(256), 0, stream>>>(Hmid, W2T, ffb2, X);
  ln_kernel    <<<dim3(8192), dim3(256), 0, stream>>>(X, seq, embed, lng, lnb, Hbf, Hlast);
  gemm_bt<512, 1024, 2><<<dim3(256, 8), dim3(256), 0, stream>>>(Hbf, WkvT, bkv, KV);
  qproj_kernel <<<dim3(128), dim3(64), 0, stream>>>(Hlast, wq, bq, qbuf);
  scan_kernel  <<<dim3(512), dim3(64), 0, stream>>>(KV, qbuf, ctx);
  opproj_kernel<<<dim3(32), dim3(256), 0, stream>>>(ctx, wop, bop, o1t);
  outproj_kernel<<<dim3(125), dim3(256), 0, stream>>>(o1t, wout, bout, (float*)d_out);
}

// Round 2
// 982.012 us; speedup vs baseline: 1.4881x; 1.4881x over previous
//
#include <hip/hip_runtime.h>
#include <hip/hip_bf16.h>

#define B_   16
#define L_   2048
#define H_   512
#define NH_  8
#define HH_  64
#define V_   32000
#define T_   32768
#define H2_  1024
#define LM_  2047   // L-1
#define DPF_ 8      // scan prefetch depth

typedef __attribute__((ext_vector_type(8))) short  short8;
typedef __attribute__((ext_vector_type(4))) float  floatx4;

__device__ inline unsigned short f2b(float x) {
  __hip_bfloat16 h = __float2bfloat16(x);
  return *reinterpret_cast<unsigned short*>(&h);
}

// ---------------------------------------------------------------- prep
// Transpose + bf16-cast weights: W1T[n][k], W2T[n][k], WkvT[j][h] (j = n*64+d for k-heads, 512+n*64+d for v-heads)
__global__ __launch_bounds__(256) void prep_kernel(
    const float* __restrict__ w1, const float* __restrict__ w2,
    const float* __restrict__ wk, const float* __restrict__ wv,
    const float* __restrict__ bk, const float* __restrict__ bv,
    unsigned short* __restrict__ W1T, unsigned short* __restrict__ W2T,
    unsigned short* __restrict__ WkvT, float* __restrict__ bkv)
{
  int id = blockIdx.x * 256 + threadIdx.x;   // 524288 threads
  { // W1T: (1024 x 512) from ff_w1 (512 x 1024)
    int n = id >> 9, k = id & 511;
    W1T[id] = f2b(w1[(size_t)k * H2_ + n]);
  }
  { // W2T: (512 x 1024) from ff_w2 (1024 x 512)
    int n = id >> 10, k = id & 1023;
    W2T[id] = f2b(w2[(size_t)k * H_ + n]);
  }
  { // WkvT: (1024 x 512); wk/wv are (NH, H, HH)
    int j = id >> 9, h = id & 511;
    float val;
    if (j < 512) val = wk[((size_t)(j >> 6) * H_ + h) * HH_ + (j & 63)];
    else { int jj = j - 512; val = wv[((size_t)(jj >> 6) * H_ + h) * HH_ + (jj & 63)]; }
    WkvT[id] = f2b(val);
  }
  if (id < 1024) bkv[id] = (id < 512) ? bk[id] : bv[id - 512];
}

// ---------------------------------------------------------------- gather
// E[t][h] = bf16(embed[seq[t]][h]); one wave per token
__global__ __launch_bounds__(256) void gather_kernel(
    const int* __restrict__ seq, const float* __restrict__ embed,
    unsigned short* __restrict__ E)
{
  int t = blockIdx.x * 4 + (threadIdx.x >> 6);
  int lane = threadIdx.x & 63;
  const float* er = embed + (size_t)seq[t] * H_;
  float4 a = *(const float4*)(er + lane * 8);
  float4 b = *(const float4*)(er + lane * 8 + 4);
  uint4 o;
  o.x = (unsigned)f2b(a.x) | ((unsigned)f2b(a.y) << 16);
  o.y = (unsigned)f2b(a.z) | ((unsigned)f2b(a.w) << 16);
  o.z = (unsigned)f2b(b.x) | ((unsigned)f2b(b.y) << 16);
  o.w = (unsigned)f2b(b.z) | ((unsigned)f2b(b.w) << 16);
  *(uint4*)(E + (size_t)t * H_ + lane * 8) = o;
}

// ---------------------------------------------------------------- GEMM
// C[M][N] = A[M][K] @ BT[N][K]^T + bias, 128x128 tile, BK=64, 4 waves.
// EPI 0: relu -> bf16 store (stride NDIM)
// EPI 1: f32 store (stride NDIM)
// EPI 2: f32 store remapped to KV[(l*16+b)*1024 + col], skip l==2047
template<int KDIM, int NDIM, int EPI>
__global__ __launch_bounds__(256) void gemm_bt(
    const unsigned short* __restrict__ A, const unsigned short* __restrict__ BT,
    const float* __restrict__ bias, void* __restrict__ outp)
{
  __shared__ uint4 smv[2048];                 // 32 KiB: As 16K + Bs 16K
  char* As = (char*)smv;
  char* Bs = As + 16384;
  const int tid = threadIdx.x;
  const int t0 = blockIdx.x * 128;
  const int n0 = blockIdx.y * 128;
  const int wid = tid >> 6, lane = tid & 63;
  const int wm = wid >> 1, wn = wid & 1;
  const int lhi = lane >> 4, llo = lane & 15;

  floatx4 acc[4][4];
  #pragma unroll
  for (int m = 0; m < 4; ++m)
    #pragma unroll
    for (int n = 0; n < 4; ++n)
      acc[m][n] = (floatx4){0.f, 0.f, 0.f, 0.f};

  for (int k0 = 0; k0 < KDIM; k0 += 64) {
    #pragma unroll
    for (int i = 0; i < 4; ++i) {            // stage 128x64 bf16 for A and B
      int idx = tid + i * 256;               // 0..1023 16B-chunks
      int row = idx >> 3, c = idx & 7;
      uint4 va = *(const uint4*)(A  + (size_t)(t0 + row) * KDIM + k0 + c * 8);
      uint4 vb = *(const uint4*)(BT + (size_t)(n0 + row) * KDIM + k0 + c * 8);
      int off = row * 128 + ((c * 16) ^ ((row & 7) << 4));   // XOR swizzle (G4)
      *(uint4*)(As + off) = va;
      *(uint4*)(Bs + off) = vb;
    }
    __syncthreads();
    #pragma unroll
    for (int kk = 0; kk < 2; ++kk) {
      short8 af[4], bfr[4];
      #pragma unroll
      for (int s = 0; s < 4; ++s) {
        int arow = wm * 64 + s * 16 + llo;
        af[s]  = *(const short8*)(As + arow * 128 + ((kk * 64 + lhi * 16) ^ ((arow & 7) << 4)));
        int brow = wn * 64 + s * 16 + llo;
        bfr[s] = *(const short8*)(Bs + brow * 128 + ((kk * 64 + lhi * 16) ^ ((brow & 7) << 4)));
      }
      #pragma unroll
      for (int m = 0; m < 4; ++m)
        #pragma unroll
        for (int n = 0; n < 4; ++n)
          acc[m][n] = __builtin_amdgcn_mfma_f32_16x16x32_bf16(af[m], bfr[n], acc[m][n], 0, 0, 0);
    }
    __syncthreads();
  }

  #pragma unroll
  for (int m = 0; m < 4; ++m) {
    int grow0 = t0 + wm * 64 + m * 16 + lhi * 4;   // C/D: row=(lane>>4)*4+r, col=lane&15
    #pragma unroll
    for (int n = 0; n < 4; ++n) {
      int gcol = n0 + wn * 64 + n * 16 + llo;
      float bb = bias[gcol];
      #pragma unroll
      for (int r = 0; r < 4; ++r) {
        int grow = grow0 + r;
        float v = acc[m][n][r] + bb;
        if (EPI == 0) {
          v = fmaxf(v, 0.f);
          ((unsigned short*)outp)[(size_t)grow * NDIM + gcol] = f2b(v);
        } else if (EPI == 1) {
          ((float*)outp)[(size_t)grow * NDIM + gcol] = v;
        } else {
          int l = grow & (L_ - 1), b = grow >> 11;
          if (l != LM_)
            ((float*)outp)[((size_t)(l * B_ + b)) * H2_ + gcol] = v;
        }
      }
    }
  }
}

// ---------------------------------------------------------------- LN
// x = X[t] + embed[seq[t]]; h = (x-mu)*rsqrt(var+1e-5)*g + b -> bf16; last token per batch also f32
__global__ __launch_bounds__(256) void ln_kernel(
    const float* __restrict__ X, const int* __restrict__ seq,
    const float* __restrict__ embed, const float* __restrict__ gam,
    const float* __restrict__ bet, unsigned short* __restrict__ Hbf,
    float* __restrict__ Hlast)
{
  int t = blockIdx.x * 4 + (threadIdx.x >> 6);
  int lane = threadIdx.x & 63;
  const float* xr = X + (size_t)t * H_;
  const float* er = embed + (size_t)seq[t] * H_;
  float4 x0 = *(const float4*)(xr + lane * 8);
  float4 x1 = *(const float4*)(xr + lane * 8 + 4);
  float4 e0 = *(const float4*)(er + lane * 8);
  float4 e1 = *(const float4*)(er + lane * 8 + 4);
  float xs[8] = {x0.x + e0.x, x0.y + e0.y, x0.z + e0.z, x0.w + e0.w,
                 x1.x + e1.x, x1.y + e1.y, x1.z + e1.z, x1.w + e1.w};
  float sum = 0.f, sq = 0.f;
  #pragma unroll
  for (int j = 0; j < 8; ++j) { sum += xs[j]; sq = fmaf(xs[j], xs[j], sq); }
  #pragma unroll
  for (int m = 1; m < 64; m <<= 1) { sum += __shfl_xor(sum, m); sq += __shfl_xor(sq, m); }
  float mu = sum * (1.f / H_);
  float var = sq * (1.f / H_) - mu * mu;
  float rs = rsqrtf(var + 1e-5f);
  float4 g0 = *(const float4*)(gam + lane * 8);
  float4 g1 = *(const float4*)(gam + lane * 8 + 4);
  float4 b0 = *(const float4*)(bet + lane * 8);
  float4 b1 = *(const float4*)(bet + lane * 8 + 4);
  float gs[8] = {g0.x, g0.y, g0.z, g0.w, g1.x, g1.y, g1.z, g1.w};
  float bs[8] = {b0.x, b0.y, b0.z, b0.w, b1.x, b1.y, b1.z, b1.w};
  float h[8];
  #pragma unroll
  for (int j = 0; j < 8; ++j) h[j] = (xs[j] - mu) * rs * gs[j] + bs[j];
  uint4 o;
  o.x = (unsigned)f2b(h[0]) | ((unsigned)f2b(h[1]) << 16);
  o.y = (unsigned)f2b(h[2]) | ((unsigned)f2b(h[3]) << 16);
  o.z = (unsigned)f2b(h[4]) | ((unsigned)f2b(h[5]) << 16);
  o.w = (unsigned)f2b(h[6]) | ((unsigned)f2b(h[7]) << 16);
  *(uint4*)(Hbf + (size_t)t * H_ + lane * 8) = o;
  if ((t & (L_ - 1)) == LM_) {
    int bi = t >> 11;
    #pragma unroll
    for (int j = 0; j < 8; ++j) Hlast[bi * H_ + lane * 8 + j] = h[j];
  }
}

// ---------------------------------------------------------------- q projection (fp32, exact path)
__global__ __launch_bounds__(64) void qproj_kernel(
    const float* __restrict__ Hlast, const float* __restrict__ wq,
    const float* __restrict__ bq, float* __restrict__ qbuf)
{
  int b = blockIdx.x >> 3, n = blockIdx.x & 7;
  int d = threadIdx.x;
  float acc = bq[n * 64 + d];
  const float* w = wq + (size_t)n * H_ * HH_ + d;
  const float* h = Hlast + b * H_;
  for (int k = 0; k < H_; ++k) acc = fmaf(h[k], w[(size_t)k * HH_], acc);
  qbuf[b * H_ + n * 64 + d] = acc;
}

// ---------------------------------------------------------------- scan (delta rule), fp32
// 512 blocks of 1 wave; block = (b,n,rowgroup of 16 rows). Thread (il,g): rows i=rg*16+il, cols g*16..g*16+15.
// Deep register prefetch (depth DPF_=8): loads for step l+8 issue at step l, so
// L3/HBM latency (~500-900cy) is covered by 8 steps of dependent-chain compute.
__device__ inline void load_kv(const float* __restrict__ base, int l, int g, int i,
                               float (&kr)[16], float& vi) {
  const float* p = base + (size_t)l * (B_ * H2_) + g * 16;
  float4 a = *(const float4*)(p);
  float4 b = *(const float4*)(p + 4);
  float4 c = *(const float4*)(p + 8);
  float4 d = *(const float4*)(p + 12);
  kr[0]=a.x; kr[1]=a.y; kr[2]=a.z; kr[3]=a.w;
  kr[4]=b.x; kr[5]=b.y; kr[6]=b.z; kr[7]=b.w;
  kr[8]=c.x; kr[9]=c.y; kr[10]=c.z; kr[11]=c.w;
  kr[12]=d.x; kr[13]=d.y; kr[14]=d.z; kr[15]=d.w;
  vi = base[(size_t)l * (B_ * H2_) + 512 + i];
}

__device__ inline void delta_step(float (&M)[16], const float (&kr)[16], float vi) {
  float p0=0,p1=0,p2=0,p3=0, s0=0,s1=0,s2=0,s3=0;
  #pragma unroll
  for (int c = 0; c < 4; ++c) {
    p0 = fmaf(M[c],    kr[c],    p0);
    p1 = fmaf(M[c+4],  kr[c+4],  p1);
    p2 = fmaf(M[c+8],  kr[c+8],  p2);
    p3 = fmaf(M[c+12], kr[c+12], p3);
    s0 = fmaf(kr[c],    kr[c],    s0);
    s1 = fmaf(kr[c+4],  kr[c+4],  s1);
    s2 = fmaf(kr[c+8],  kr[c+8],  s2);
    s3 = fmaf(kr[c+12], kr[c+12], s3);
  }
  float p = (p0 + p1) + (p2 + p3);
  float s = (s0 + s1) + (s2 + s3);
  p += __shfl_xor(p, 1); p += __shfl_xor(p, 2);
  s += __shfl_xor(s, 1); s += __shfl_xor(s, 2);
  // v_rcp_f32 (~1 ulp) instead of exact-div sequence: shaves ~20cy off the serial chain
  float d = vi - p * __builtin_amdgcn_rcpf(s + 1e-6f);
  #pragma unroll
  for (int c = 0; c < 16; ++c) M[c] = fmaf(d, kr[c], M[c]);
}

__global__ __launch_bounds__(64) void scan_kernel(
    const float* __restrict__ KV, const float* __restrict__ qbuf,
    float* __restrict__ ctx)
{
  int pair = blockIdx.x >> 2, rg = blockIdx.x & 3;
  int b = pair >> 3, n = pair & 7;
  int lane = threadIdx.x;
  int il = lane >> 2, g = lane & 3;
  int i = rg * 16 + il;
  const float* base = KV + (size_t)b * H2_ + n * 64;
  float M[16];
  #pragma unroll
  for (int c = 0; c < 16; ++c) M[c] = 0.f;

  float kr[DPF_][16];
  float vv[DPF_];
  #pragma unroll
  for (int j = 0; j < DPF_; ++j) load_kv(base, j, g, i, kr[j], vv[j]);

  // main: 255 * 8 = 2040 steps; slots statically indexed (full unroll) so the
  // ring stays in registers (rule #20).
  for (int bs = 0; bs < 2040; bs += DPF_) {
    #pragma unroll
    for (int j = 0; j < DPF_; ++j) {
      delta_step(M, kr[j], vv[j]);
      int lnx = bs + j + DPF_;
      if (lnx > LM_ - 1) lnx = LM_ - 1;      // clamp: over-end prefetch re-reads row 2046, never consumed
      load_kv(base, lnx, g, i, kr[j], vv[j]);
    }
  }
  // tail: steps 2040..2046 from slots 0..6
  #pragma unroll
  for (int j = 0; j < 7; ++j) delta_step(M, kr[j], vv[j]);

  // ctx[b][n*64+i] = sum_j M[i][j] q[j]
  const float* qp = qbuf + b * H_ + n * 64 + g * 16;
  float4 qa = *(const float4*)(qp);
  float4 qb = *(const float4*)(qp + 4);
  float4 qc = *(const float4*)(qp + 8);
  float4 qd = *(const float4*)(qp + 12);
  float q[16] = {qa.x,qa.y,qa.z,qa.w, qb.x,qb.y,qb.z,qb.w,
                 qc.x,qc.y,qc.z,qc.w, qd.x,qd.y,qd.z,qd.w};
  float p = 0.f;
  #pragma unroll
  for (int c = 0; c < 16; ++c) p = fmaf(M[c], q[c], p);
  p += __shfl_xor(p, 1); p += __shfl_xor(p, 2);
  if (g == 0) ctx[b * H_ + n * 64 + i] = p;
}

// ---------------------------------------------------------------- output projections (fp32)
__global__ __launch_bounds__(256) void opproj_kernel(
    const float* __restrict__ ctx, const float* __restrict__ wop,
    const float* __restrict__ bop, float* __restrict__ o1t)
{
  int id = blockIdx.x * 256 + threadIdx.x;   // 8192
  int b = id >> 9, h = id & 511;
  float acc = bop[h];
  const float* c = ctx + b * H_;
  for (int k = 0; k < H_; ++k) acc = fmaf(c[k], wop[(size_t)k * H_ + h], acc);
  o1t[h * B_ + b] = acc;                     // [h][b] for vectorized reads downstream
}

__global__ __launch_bounds__(256) void outproj_kernel(
    const float* __restrict__ o1t, const float* __restrict__ wout,
    const float* __restrict__ bout, float* __restrict__ out)
{
  __shared__ float o1s[H_ * B_];             // 32 KiB
  for (int idx = threadIdx.x; idx < H_ * B_; idx += 256) o1s[idx] = o1t[idx];
  __syncthreads();
  int v = blockIdx.x * 256 + threadIdx.x;    // 125 blocks * 256 = 32000 exactly
  float bo = bout[v];
  float acc[B_];
  #pragma unroll
  for (int b = 0; b < B_; ++b) acc[b] = bo;
  for (int h = 0; h < H_; ++h) {
    float w = wout[(size_t)h * V_ + v];
    const float4* op = (const float4*)&o1s[h * B_];
    float4 a0 = op[0], a1 = op[1], a2 = op[2], a3 = op[3];
    float oa[16] = {a0.x,a0.y,a0.z,a0.w, a1.x,a1.y,a1.z,a1.w,
                    a2.x,a2.y,a2.z,a2.w, a3.x,a3.y,a3.z,a3.w};
    #pragma unroll
    for (int b = 0; b < B_; ++b) acc[b] = fmaf(oa[b], w, acc[b]);
  }
  #pragma unroll
  for (int b = 0; b < B_; ++b) out[(size_t)b * V_ + v] = acc[b];
}

// ---------------------------------------------------------------- launch
extern "C" void kernel_launch(void* const* d_in, const int* in_sizes, int n_in,
                              void* d_out, int out_size, void* d_ws, size_t ws_size,
                              hipStream_t stream)
{
  const int*   seq   = (const int*)d_in[0];
  const float* embed = (const float*)d_in[1];
  const float* ffw1  = (const float*)d_in[2];
  const float* ffb1  = (const float*)d_in[3];
  const float* ffw2  = (const float*)d_in[4];
  const float* ffb2  = (const float*)d_in[5];
  const float* lng   = (const float*)d_in[6];
  const float* lnb   = (const float*)d_in[7];
  const float* wk    = (const float*)d_in[8];
  const float* bk    = (const float*)d_in[9];
  const float* wv    = (const float*)d_in[10];
  const float* bv    = (const float*)d_in[11];
  const float* wq    = (const float*)d_in[12];
  const float* bq    = (const float*)d_in[13];
  const float* wop   = (const float*)d_in[14];
  const float* bop   = (const float*)d_in[15];
  const float* wout  = (const float*)d_in[16];
  const float* bout  = (const float*)d_in[17];

  char* ws = (char*)d_ws;
  const size_t MB = 1024 * 1024;
  unsigned short* W1T   = (unsigned short*)(ws + 0 * MB);   // 1 MB
  unsigned short* W2T   = (unsigned short*)(ws + 1 * MB);   // 1 MB
  unsigned short* WkvT  = (unsigned short*)(ws + 2 * MB);   // 1 MB
  float*          bkv   = (float*)(ws + 3 * MB);            // 4 KB
  float*          Hlast = (float*)(ws + 3 * MB + 8192);     // 32 KB
  float*          qbuf  = (float*)(ws + 3 * MB + 8192 + 32768);
  float*          ctx   = (float*)(ws + 3 * MB + 8192 + 2 * 32768);
  float*          o1t   = (float*)(ws + 3 * MB + 8192 + 3 * 32768);
  unsigned short* E     = (unsigned short*)(ws + 4 * MB);   // 32 MB  [4,36)
  unsigned short* Hbf   = E;                                // reuses E after FFN consumes it
  unsigned short* Hmid  = (unsigned short*)(ws + 36 * MB);  // 64 MB  [36,100)
  float*          X     = (float*)(ws + 100 * MB);          // 64 MB  [100,164)
  float*          KV    = (float*)(ws + 36 * MB);           // 128 MB [36,164) reuses Hmid+X after LN

  prep_kernel  <<<dim3(2048), dim3(256), 0, stream>>>(ffw1, ffw2, wk, wv, bk, bv, W1T, W2T, WkvT, bkv);
  gather_kernel<<<dim3(8192), dim3(256), 0, stream>>>(seq, embed, E);
  gemm_bt<512, 1024, 0><<<dim3(256, 8), dim3(256), 0, stream>>>(E, W1T, ffb1, Hmid);
  gemm_bt<1024, 512, 1><<<dim3(256, 4), dim3(256), 0, stream>>>(Hmid, W2T, ffb2, X);
  ln_kernel    <<<dim3(8192), dim3(256), 0, stream>>>(X, seq, embed, lng, lnb, Hbf, Hlast);
  gemm_bt<512, 1024, 2><<<dim3(256, 8), dim3(256), 0, stream>>>(Hbf, WkvT, bkv, KV);
  qproj_kernel <<<dim3(128), dim3(64), 0, stream>>>(Hlast, wq, bq, qbuf);
  scan_kernel  <<<dim3(512), dim3(64), 0, stream>>>(KV, qbuf, ctx);
  opproj_kernel<<<dim3(32), dim3(256), 0, stream>>>(ctx, wop, bop, o1t);
  outproj_kernel<<<dim3(125), dim3(256), 0, stream>>>(o1t, wout, bout, (float*)d_out);
}

// Round 3
// 838.087 us; speedup vs baseline: 1.7437x; 1.1717x over previous
//
#include <hip/hip_runtime.h>
#include <hip/hip_bf16.h>

#define B_   16
#define L_   2048
#define H_   512
#define NH_  8
#define HH_  64
#define V_   32000
#define T_   32768
#define H2_  1024
#define LM_  2047   // L-1
#define DPF_ 12     // scan prefetch depth (12*4=48 outstanding vmem < 63 vmcnt cap)

typedef __attribute__((ext_vector_type(8))) short  short8;
typedef __attribute__((ext_vector_type(4))) float  floatx4;

__device__ inline unsigned short f2b(float x) {
  __hip_bfloat16 h = __float2bfloat16(x);
  return *reinterpret_cast<unsigned short*>(&h);
}

// DPP-based partial-wave sum reduce: pure VALU (~8cy) vs ds_bpermute (~120cy).
// 0xB1 = quad_perm(1,0,3,2) -> xor1 ; 0x4E = quad_perm(2,3,0,1) -> xor2 ;
// 0x141 = row_half_mirror -> completes 8-lane aligned-group reduction.
template<int CTRL>
__device__ inline float dpp_add(float x) {
  union { float f; int i; } u, r;
  u.f = x;
  r.i = __builtin_amdgcn_update_dpp(u.i, u.i, CTRL, 0xF, 0xF, false);
  return x + r.f;
}

// ---------------------------------------------------------------- prep
__global__ __launch_bounds__(256) void prep_kernel(
    const float* __restrict__ w1, const float* __restrict__ w2,
    const float* __restrict__ wk, const float* __restrict__ wv,
    const float* __restrict__ bk, const float* __restrict__ bv,
    unsigned short* __restrict__ W1T, unsigned short* __restrict__ W2T,
    unsigned short* __restrict__ WkvT, float* __restrict__ bkv)
{
  int id = blockIdx.x * 256 + threadIdx.x;   // 524288 threads
  { // W1T: (1024 x 512) from ff_w1 (512 x 1024)
    int n = id >> 9, k = id & 511;
    W1T[id] = f2b(w1[(size_t)k * H2_ + n]);
  }
  { // W2T: (512 x 1024) from ff_w2 (1024 x 512)
    int n = id >> 10, k = id & 1023;
    W2T[id] = f2b(w2[(size_t)k * H_ + n]);
  }
  { // WkvT: (1024 x 512); wk/wv are (NH, H, HH)
    int j = id >> 9, h = id & 511;
    float val;
    if (j < 512) val = wk[((size_t)(j >> 6) * H_ + h) * HH_ + (j & 63)];
    else { int jj = j - 512; val = wv[((size_t)(jj >> 6) * H_ + h) * HH_ + (jj & 63)]; }
    WkvT[id] = f2b(val);
  }
  if (id < 1024) bkv[id] = (id < 512) ? bk[id] : bv[id - 512];
}

// ---------------------------------------------------------------- gather
__global__ __launch_bounds__(256) void gather_kernel(
    const int* __restrict__ seq, const float* __restrict__ embed,
    unsigned short* __restrict__ E)
{
  int t = blockIdx.x * 4 + (threadIdx.x >> 6);
  int lane = threadIdx.x & 63;
  const float* er = embed + (size_t)seq[t] * H_;
  float4 a = *(const float4*)(er + lane * 8);
  float4 b = *(const float4*)(er + lane * 8 + 4);
  uint4 o;
  o.x = (unsigned)f2b(a.x) | ((unsigned)f2b(a.y) << 16);
  o.y = (unsigned)f2b(a.z) | ((unsigned)f2b(a.w) << 16);
  o.z = (unsigned)f2b(b.x) | ((unsigned)f2b(b.y) << 16);
  o.w = (unsigned)f2b(b.z) | ((unsigned)f2b(b.w) << 16);
  *(uint4*)(E + (size_t)t * H_ + lane * 8) = o;
}

// ---------------------------------------------------------------- GEMM
// C[M][N] = A[M][K] @ BT[N][K]^T + bias, 128x128 tile, BK=64, 4 waves.
template<int KDIM, int NDIM, int EPI>
__global__ __launch_bounds__(256) void gemm_bt(
    const unsigned short* __restrict__ A, const unsigned short* __restrict__ BT,
    const float* __restrict__ bias, void* __restrict__ outp)
{
  __shared__ uint4 smv[2048];                 // 32 KiB: As 16K + Bs 16K
  char* As = (char*)smv;
  char* Bs = As + 16384;
  const int tid = threadIdx.x;
  const int t0 = blockIdx.x * 128;
  const int n0 = blockIdx.y * 128;
  const int wid = tid >> 6, lane = tid & 63;
  const int wm = wid >> 1, wn = wid & 1;
  const int lhi = lane >> 4, llo = lane & 15;

  floatx4 acc[4][4];
  #pragma unroll
  for (int m = 0; m < 4; ++m)
    #pragma unroll
    for (int n = 0; n < 4; ++n)
      acc[m][n] = (floatx4){0.f, 0.f, 0.f, 0.f};

  for (int k0 = 0; k0 < KDIM; k0 += 64) {
    #pragma unroll
    for (int i = 0; i < 4; ++i) {            // stage 128x64 bf16 for A and B
      int idx = tid + i * 256;               // 0..1023 16B-chunks
      int row = idx >> 3, c = idx & 7;
      uint4 va = *(const uint4*)(A  + (size_t)(t0 + row) * KDIM + k0 + c * 8);
      uint4 vb = *(const uint4*)(BT + (size_t)(n0 + row) * KDIM + k0 + c * 8);
      int off = row * 128 + ((c * 16) ^ ((row & 7) << 4));   // XOR swizzle (G4)
      *(uint4*)(As + off) = va;
      *(uint4*)(Bs + off) = vb;
    }
    __syncthreads();
    #pragma unroll
    for (int kk = 0; kk < 2; ++kk) {
      short8 af[4], bfr[4];
      #pragma unroll
      for (int s = 0; s < 4; ++s) {
        int arow = wm * 64 + s * 16 + llo;
        af[s]  = *(const short8*)(As + arow * 128 + ((kk * 64 + lhi * 16) ^ ((arow & 7) << 4)));
        int brow = wn * 64 + s * 16 + llo;
        bfr[s] = *(const short8*)(Bs + brow * 128 + ((kk * 64 + lhi * 16) ^ ((brow & 7) << 4)));
      }
      #pragma unroll
      for (int m = 0; m < 4; ++m)
        #pragma unroll
        for (int n = 0; n < 4; ++n)
          acc[m][n] = __builtin_amdgcn_mfma_f32_16x16x32_bf16(af[m], bfr[n], acc[m][n], 0, 0, 0);
    }
    __syncthreads();
  }

  #pragma unroll
  for (int m = 0; m < 4; ++m) {
    int grow0 = t0 + wm * 64 + m * 16 + lhi * 4;   // C/D: row=(lane>>4)*4+r, col=lane&15
    #pragma unroll
    for (int n = 0; n < 4; ++n) {
      int gcol = n0 + wn * 64 + n * 16 + llo;
      float bb = bias[gcol];
      #pragma unroll
      for (int r = 0; r < 4; ++r) {
        int grow = grow0 + r;
        float v = acc[m][n][r] + bb;
        if (EPI == 0) {
          v = fmaxf(v, 0.f);
          ((unsigned short*)outp)[(size_t)grow * NDIM + gcol] = f2b(v);
        } else if (EPI == 1) {
          ((float*)outp)[(size_t)grow * NDIM + gcol] = v;
        } else {
          int l = grow & (L_ - 1), b = grow >> 11;
          if (l != LM_)
            ((float*)outp)[((size_t)(l * B_ + b)) * H2_ + gcol] = v;
        }
      }
    }
  }
}

// ---------------------------------------------------------------- LN
__global__ __launch_bounds__(256) void ln_kernel(
    const float* __restrict__ X, const int* __restrict__ seq,
    const float* __restrict__ embed, const float* __restrict__ gam,
    const float* __restrict__ bet, unsigned short* __restrict__ Hbf,
    float* __restrict__ Hlast)
{
  int t = blockIdx.x * 4 + (threadIdx.x >> 6);
  int lane = threadIdx.x & 63;
  const float* xr = X + (size_t)t * H_;
  const float* er = embed + (size_t)seq[t] * H_;
  float4 x0 = *(const float4*)(xr + lane * 8);
  float4 x1 = *(const float4*)(xr + lane * 8 + 4);
  float4 e0 = *(const float4*)(er + lane * 8);
  float4 e1 = *(const float4*)(er + lane * 8 + 4);
  float xs[8] = {x0.x + e0.x, x0.y + e0.y, x0.z + e0.z, x0.w + e0.w,
                 x1.x + e1.x, x1.y + e1.y, x1.z + e1.z, x1.w + e1.w};
  float sum = 0.f, sq = 0.f;
  #pragma unroll
  for (int j = 0; j < 8; ++j) { sum += xs[j]; sq = fmaf(xs[j], xs[j], sq); }
  #pragma unroll
  for (int m = 1; m < 64; m <<= 1) { sum += __shfl_xor(sum, m); sq += __shfl_xor(sq, m); }
  float mu = sum * (1.f / H_);
  float var = sq * (1.f / H_) - mu * mu;
  float rs = rsqrtf(var + 1e-5f);
  float4 g0 = *(const float4*)(gam + lane * 8);
  float4 g1 = *(const float4*)(gam + lane * 8 + 4);
  float4 b0 = *(const float4*)(bet + lane * 8);
  float4 b1 = *(const float4*)(bet + lane * 8 + 4);
  float gs[8] = {g0.x, g0.y, g0.z, g0.w, g1.x, g1.y, g1.z, g1.w};
  float bs[8] = {b0.x, b0.y, b0.z, b0.w, b1.x, b1.y, b1.z, b1.w};
  float h[8];
  #pragma unroll
  for (int j = 0; j < 8; ++j) h[j] = (xs[j] - mu) * rs * gs[j] + bs[j];
  uint4 o;
  o.x = (unsigned)f2b(h[0]) | ((unsigned)f2b(h[1]) << 16);
  o.y = (unsigned)f2b(h[2]) | ((unsigned)f2b(h[3]) << 16);
  o.z = (unsigned)f2b(h[4]) | ((unsigned)f2b(h[5]) << 16);
  o.w = (unsigned)f2b(h[6]) | ((unsigned)f2b(h[7]) << 16);
  *(uint4*)(Hbf + (size_t)t * H_ + lane * 8) = o;
  if ((t & (L_ - 1)) == LM_) {
    int bi = t >> 11;
    #pragma unroll
    for (int j = 0; j < 8; ++j) Hlast[bi * H_ + lane * 8 + j] = h[j];
  }
}

// ---------------------------------------------------------------- q projection (fp32, exact path)
__global__ __launch_bounds__(64) void qproj_kernel(
    const float* __restrict__ Hlast, const float* __restrict__ wq,
    const float* __restrict__ bq, float* __restrict__ qbuf)
{
  int b = blockIdx.x >> 3, n = blockIdx.x & 7;
  int d = threadIdx.x;
  float acc = bq[n * 64 + d];
  const float* w = wq + (size_t)n * H_ * HH_ + d;
  const float* h = Hlast + b * H_;
  for (int k = 0; k < H_; ++k) acc = fmaf(h[k], w[(size_t)k * HH_], acc);
  qbuf[b * H_ + n * 64 + d] = acc;
}

// ---------------------------------------------------------------- rn precompute
// rn[l*128 + b*8 + n] = 1/(||k_{l,b,n}||^2 + 1e-6). s depends only on k, not M,
// so it comes OFF the scan's serial critical path entirely.
__global__ __launch_bounds__(256) void rnk_kernel(
    const float* __restrict__ KV, float* __restrict__ rn)
{
  int w = blockIdx.x * 4 + (threadIdx.x >> 6);
  if (w >= LM_ * B_) return;                 // 32752 waves: one per (l,b)
  int lane = threadIdx.x & 63;
  int l = w >> 4, b = w & 15;
  const float* p = KV + (size_t)(l * B_ + b) * H2_ + lane * 8;
  float4 a = *(const float4*)p;
  float4 c = *(const float4*)(p + 4);
  float s = a.x*a.x + a.y*a.y + a.z*a.z + a.w*a.w
          + c.x*c.x + c.y*c.y + c.z*c.z + c.w*c.w;
  s = dpp_add<0xB1>(s); s = dpp_add<0x4E>(s); s = dpp_add<0x141>(s);
  if ((lane & 7) == 0) rn[l * 128 + b * 8 + (lane >> 3)] = 1.0f / (s + 1e-6f);
}

// ---------------------------------------------------------------- scan (delta rule), fp32
// 1024 blocks of 1 wave; block = (b,n,rowgroup of 8 rows).
// Lane = r*8+cg: row i = rg*8+r, cols cg*8..cg*8+7 (8-lane aligned groups ->
// 3-level DPP reduce, no LDS-latency cross-lane on the chain).
// rn precomputed; ring depth DPF_=12; __launch_bounds__(64,1) lifts the VGPR
// cap (R2's VGPR=140 forced the compiler to sink prefetch loads).
__device__ inline void load_kv8(const float* __restrict__ base,
                                const float* __restrict__ rnp, int l, int cg, int i,
                                float (&kr)[8], float& vi, float& rr) {
  const float* p = base + (size_t)l * (B_ * H2_) + cg * 8;
  float4 a = *(const float4*)(p);
  float4 b = *(const float4*)(p + 4);
  kr[0]=a.x; kr[1]=a.y; kr[2]=a.z; kr[3]=a.w;
  kr[4]=b.x; kr[5]=b.y; kr[6]=b.z; kr[7]=b.w;
  vi = base[(size_t)l * (B_ * H2_) + 512 + i];
  rr = rnp[l * 128];
}

__device__ inline void delta_step8(float (&M)[8], const float (&kr)[8], float vi, float rr) {
  float pa = 0.f, pb = 0.f;
  #pragma unroll
  for (int c = 0; c < 4; ++c) {
    pa = fmaf(M[c],     kr[c],     pa);
    pb = fmaf(M[c + 4], kr[c + 4], pb);
  }
  float p = pa + pb;
  p = dpp_add<0xB1>(p);    // xor1
  p = dpp_add<0x4E>(p);    // xor2
  p = dpp_add<0x141>(p);   // half-mirror -> 8-lane sum
  float d = vi - p * rr;
  #pragma unroll
  for (int c = 0; c < 8; ++c) M[c] = fmaf(d, kr[c], M[c]);
}

__global__ __launch_bounds__(64, 1) void scan_kernel(
    const float* __restrict__ KV, const float* __restrict__ rnbuf,
    const float* __restrict__ qbuf, float* __restrict__ ctx)
{
  int pair = blockIdx.x >> 3, rg = blockIdx.x & 7;
  int b = pair >> 3, n = pair & 7;
  int lane = threadIdx.x;
  int r = lane >> 3, cg = lane & 7;
  int i = rg * 8 + r;
  const float* base = KV + (size_t)b * H2_ + n * 64;
  const float* rnp = rnbuf + b * 8 + n;
  float M[8];
  #pragma unroll
  for (int c = 0; c < 8; ++c) M[c] = 0.f;

  float kr[DPF_][8];
  float vv[DPF_], rr[DPF_];
  #pragma unroll
  for (int j = 0; j < DPF_; ++j) load_kv8(base, rnp, j, cg, i, kr[j], vv[j], rr[j]);

  // main: 170 * 12 = 2040 steps; ring statically indexed (full unroll, rule #20)
  for (int bs = 0; bs < 2040; bs += DPF_) {
    #pragma unroll
    for (int j = 0; j < DPF_; ++j) {
      delta_step8(M, kr[j], vv[j], rr[j]);
      int lnx = bs + j + DPF_;
      if (lnx > LM_ - 1) lnx = LM_ - 1;      // over-end prefetch re-reads row 2046, never consumed
      load_kv8(base, rnp, lnx, cg, i, kr[j], vv[j], rr[j]);
    }
  }
  // tail: steps 2040..2046 from slots 0..6
  #pragma unroll
  for (int j = 0; j < 7; ++j) delta_step8(M, kr[j], vv[j], rr[j]);

  // ctx[b][n*64+i] = sum_j M[i][j] q[j]
  const float* qp = qbuf + b * H_ + n * 64 + cg * 8;
  float4 qa = *(const float4*)(qp);
  float4 qb = *(const float4*)(qp + 4);
  float q[8] = {qa.x, qa.y, qa.z, qa.w, qb.x, qb.y, qb.z, qb.w};
  float p = 0.f;
  #pragma unroll
  for (int c = 0; c < 8; ++c) p = fmaf(M[c], q[c], p);
  p = dpp_add<0xB1>(p); p = dpp_add<0x4E>(p); p = dpp_add<0x141>(p);
  if (cg == 0) ctx[b * H_ + n * 64 + i] = p;
}

// ---------------------------------------------------------------- output projections (fp32)
__global__ __launch_bounds__(256) void opproj_kernel(
    const float* __restrict__ ctx, const float* __restrict__ wop,
    const float* __restrict__ bop, float* __restrict__ o1t)
{
  int id = blockIdx.x * 256 + threadIdx.x;   // 8192
  int b = id >> 9, h = id & 511;
  float acc = bop[h];
  const float* c = ctx + b * H_;
  for (int k = 0; k < H_; ++k) acc = fmaf(c[k], wop[(size_t)k * H_ + h], acc);
  o1t[h * B_ + b] = acc;                     // [h][b] for vectorized reads downstream
}

__global__ __launch_bounds__(256) void outproj_kernel(
    const float* __restrict__ o1t, const float* __restrict__ wout,
    const float* __restrict__ bout, float* __restrict__ out)
{
  __shared__ float o1s[H_ * B_];             // 32 KiB
  for (int idx = threadIdx.x; idx < H_ * B_; idx += 256) o1s[idx] = o1t[idx];
  __syncthreads();
  int v = blockIdx.x * 256 + threadIdx.x;    // 125 blocks * 256 = 32000 exactly
  float bo = bout[v];
  float acc[B_];
  #pragma unroll
  for (int b = 0; b < B_; ++b) acc[b] = bo;
  for (int h = 0; h < H_; ++h) {
    float w = wout[(size_t)h * V_ + v];
    const float4* op = (const float4*)&o1s[h * B_];
    float4 a0 = op[0], a1 = op[1], a2 = op[2], a3 = op[3];
    float oa[16] = {a0.x,a0.y,a0.z,a0.w, a1.x,a1.y,a1.z,a1.w,
                    a2.x,a2.y,a2.z,a2.w, a3.x,a3.y,a3.z,a3.w};
    #pragma unroll
    for (int b = 0; b < B_; ++b) acc[b] = fmaf(oa[b], w, acc[b]);
  }
  #pragma unroll
  for (int b = 0; b < B_; ++b) out[(size_t)b * V_ + v] = acc[b];
}

// ---------------------------------------------------------------- launch
extern "C" void kernel_launch(void* const* d_in, const int* in_sizes, int n_in,
                              void* d_out, int out_size, void* d_ws, size_t ws_size,
                              hipStream_t stream)
{
  const int*   seq   = (const int*)d_in[0];
  const float* embed = (const float*)d_in[1];
  const float* ffw1  = (const float*)d_in[2];
  const float* ffb1  = (const float*)d_in[3];
  const float* ffw2  = (const float*)d_in[4];
  const float* ffb2  = (const float*)d_in[5];
  const float* lng   = (const float*)d_in[6];
  const float* lnb   = (const float*)d_in[7];
  const float* wk    = (const float*)d_in[8];
  const float* bk    = (const float*)d_in[9];
  const float* wv    = (const float*)d_in[10];
  const float* bv    = (const float*)d_in[11];
  const float* wq    = (const float*)d_in[12];
  const float* bq    = (const float*)d_in[13];
  const float* wop   = (const float*)d_in[14];
  const float* bop   = (const float*)d_in[15];
  const float* wout  = (const float*)d_in[16];
  const float* bout  = (const float*)d_in[17];

  char* ws = (char*)d_ws;
  const size_t MB = 1024 * 1024;
  unsigned short* W1T   = (unsigned short*)(ws + 0 * MB);   // 1 MB
  unsigned short* W2T   = (unsigned short*)(ws + 1 * MB);   // 1 MB
  unsigned short* WkvT  = (unsigned short*)(ws + 2 * MB);   // 1 MB
  float*          bkv   = (float*)(ws + 3 * MB);            // 4 KB
  float*          Hlast = (float*)(ws + 3 * MB + 8192);     // 32 KB
  float*          qbuf  = (float*)(ws + 3 * MB + 8192 + 32768);
  float*          ctx   = (float*)(ws + 3 * MB + 8192 + 2 * 32768);
  float*          o1t   = (float*)(ws + 3 * MB + 8192 + 3 * 32768);
  unsigned short* E     = (unsigned short*)(ws + 4 * MB);   // 32 MB  [4,36)
  unsigned short* Hbf   = E;                                // reuses E after FFN consumes it
  float*          rn    = (float*)(ws + 4 * MB);            // 1 MB; reuses Hbf region (dead after kv-gemm)
  unsigned short* Hmid  = (unsigned short*)(ws + 36 * MB);  // 64 MB  [36,100)
  float*          X     = (float*)(ws + 100 * MB);          // 64 MB  [100,164)
  float*          KV    = (float*)(ws + 36 * MB);           // 128 MB [36,164) reuses Hmid+X after LN

  prep_kernel  <<<dim3(2048), dim3(256), 0, stream>>>(ffw1, ffw2, wk, wv, bk, bv, W1T, W2T, WkvT, bkv);
  gather_kernel<<<dim3(8192), dim3(256), 0, stream>>>(seq, embed, E);
  gemm_bt<512, 1024, 0><<<dim3(256, 8), dim3(256), 0, stream>>>(E, W1T, ffb1, Hmid);
  gemm_bt<1024, 512, 1><<<dim3(256, 4), dim3(256), 0, stream>>>(Hmid, W2T, ffb2, X);
  ln_kernel    <<<dim3(8192), dim3(256), 0, stream>>>(X, seq, embed, lng, lnb, Hbf, Hlast);
  gemm_bt<512, 1024, 2><<<dim3(256, 8), dim3(256), 0, stream>>>(Hbf, WkvT, bkv, KV);
  rnk_kernel   <<<dim3(8188), dim3(256), 0, stream>>>(KV, rn);
  qproj_kernel <<<dim3(128), dim3(64), 0, stream>>>(Hlast, wq, bq, qbuf);
  scan_kernel  <<<dim3(1024), dim3(64), 0, stream>>>(KV, rn, qbuf, ctx);
  opproj_kernel<<<dim3(32), dim3(256), 0, stream>>>(ctx, wop, bop, o1t);
  outproj_kernel<<<dim3(125), dim3(256), 0, stream>>>(o1t, wout, bout, (float*)d_out);
}

// Round 4
// 702.609 us; speedup vs baseline: 2.0799x; 1.1928x over previous
//
#include <hip/hip_runtime.h>
#include <hip/hip_bf16.h>

#define B_   16
#define L_   2048
#define H_   512
#define NH_  8
#define HH_  64
#define V_   32000
#define T_   32768
#define H2_  1024
#define LM_  2047   // L-1
#define SB_  32     // scan steps per staged batch
#define NBATCH_ 64  // 64*32 = 2048 slots; 2047 real steps

typedef __attribute__((ext_vector_type(8))) short  short8;
typedef __attribute__((ext_vector_type(4))) float  floatx4;
typedef unsigned int u32;

__device__ inline unsigned short f2b(float x) {
  __hip_bfloat16 h = __float2bfloat16(x);
  return *reinterpret_cast<unsigned short*>(&h);
}

// async global->LDS, 16B per lane: LDS dest is wave-uniform base + lane*16
// (linear, matches global row order -> rule #21 satisfied, no swizzle).
__device__ inline void gload_lds16(const float* g, float* l) {
  __builtin_amdgcn_global_load_lds(
      (const __attribute__((address_space(1))) u32*)g,
      (__attribute__((address_space(3))) u32*)l, 16, 0, 0);
}

// DPP partial-wave sum reduce (pure VALU): 0xB1 xor1, 0x4E xor2, 0x141 half-mirror
template<int CTRL>
__device__ inline float dpp_add(float x) {
  union { float f; int i; } u, r;
  u.f = x;
  r.i = __builtin_amdgcn_update_dpp(u.i, u.i, CTRL, 0xF, 0xF, false);
  return x + r.f;
}

// ---------------------------------------------------------------- prep
__global__ __launch_bounds__(256) void prep_kernel(
    const float* __restrict__ w1, const float* __restrict__ w2,
    const float* __restrict__ wk, const float* __restrict__ wv,
    const float* __restrict__ bk, const float* __restrict__ bv,
    unsigned short* __restrict__ W1T, unsigned short* __restrict__ W2T,
    unsigned short* __restrict__ WkvT, float* __restrict__ bkv)
{
  int id = blockIdx.x * 256 + threadIdx.x;   // 524288 threads
  { int n = id >> 9, k = id & 511;
    W1T[id] = f2b(w1[(size_t)k * H2_ + n]); }
  { int n = id >> 10, k = id & 1023;
    W2T[id] = f2b(w2[(size_t)k * H_ + n]); }
  { int j = id >> 9, h = id & 511;
    float val;
    if (j < 512) val = wk[((size_t)(j >> 6) * H_ + h) * HH_ + (j & 63)];
    else { int jj = j - 512; val = wv[((size_t)(jj >> 6) * H_ + h) * HH_ + (jj & 63)]; }
    WkvT[id] = f2b(val); }
  if (id < 1024) bkv[id] = (id < 512) ? bk[id] : bv[id - 512];
}

// ---------------------------------------------------------------- gather
__global__ __launch_bounds__(256) void gather_kernel(
    const int* __restrict__ seq, const float* __restrict__ embed,
    unsigned short* __restrict__ E)
{
  int t = blockIdx.x * 4 + (threadIdx.x >> 6);
  int lane = threadIdx.x & 63;
  const float* er = embed + (size_t)seq[t] * H_;
  float4 a = *(const float4*)(er + lane * 8);
  float4 b = *(const float4*)(er + lane * 8 + 4);
  uint4 o;
  o.x = (unsigned)f2b(a.x) | ((unsigned)f2b(a.y) << 16);
  o.y = (unsigned)f2b(a.z) | ((unsigned)f2b(a.w) << 16);
  o.z = (unsigned)f2b(b.x) | ((unsigned)f2b(b.y) << 16);
  o.w = (unsigned)f2b(b.z) | ((unsigned)f2b(b.w) << 16);
  *(uint4*)(E + (size_t)t * H_ + lane * 8) = o;
}

// ---------------------------------------------------------------- GEMM
// C[M][N] = A[M][K] @ BT[N][K]^T + bias, 128x128 tile, BK=64, 4 waves.
template<int KDIM, int NDIM, int EPI>
__global__ __launch_bounds__(256) void gemm_bt(
    const unsigned short* __restrict__ A, const unsigned short* __restrict__ BT,
    const float* __restrict__ bias, void* __restrict__ outp)
{
  __shared__ uint4 smv[2048];                 // 32 KiB: As 16K + Bs 16K
  char* As = (char*)smv;
  char* Bs = As + 16384;
  const int tid = threadIdx.x;
  const int t0 = blockIdx.x * 128;
  const int n0 = blockIdx.y * 128;
  const int wid = tid >> 6, lane = tid & 63;
  const int wm = wid >> 1, wn = wid & 1;
  const int lhi = lane >> 4, llo = lane & 15;

  floatx4 acc[4][4];
  #pragma unroll
  for (int m = 0; m < 4; ++m)
    #pragma unroll
    for (int n = 0; n < 4; ++n)
      acc[m][n] = (floatx4){0.f, 0.f, 0.f, 0.f};

  for (int k0 = 0; k0 < KDIM; k0 += 64) {
    #pragma unroll
    for (int i = 0; i < 4; ++i) {            // stage 128x64 bf16 for A and B
      int idx = tid + i * 256;               // 0..1023 16B-chunks
      int row = idx >> 3, c = idx & 7;
      uint4 va = *(const uint4*)(A  + (size_t)(t0 + row) * KDIM + k0 + c * 8);
      uint4 vb = *(const uint4*)(BT + (size_t)(n0 + row) * KDIM + k0 + c * 8);
      int off = row * 128 + ((c * 16) ^ ((row & 7) << 4));   // XOR swizzle (G4)
      *(uint4*)(As + off) = va;
      *(uint4*)(Bs + off) = vb;
    }
    __syncthreads();
    #pragma unroll
    for (int kk = 0; kk < 2; ++kk) {
      short8 af[4], bfr[4];
      #pragma unroll
      for (int s = 0; s < 4; ++s) {
        int arow = wm * 64 + s * 16 + llo;
        af[s]  = *(const short8*)(As + arow * 128 + ((kk * 64 + lhi * 16) ^ ((arow & 7) << 4)));
        int brow = wn * 64 + s * 16 + llo;
        bfr[s] = *(const short8*)(Bs + brow * 128 + ((kk * 64 + lhi * 16) ^ ((brow & 7) << 4)));
      }
      #pragma unroll
      for (int m = 0; m < 4; ++m)
        #pragma unroll
        for (int n = 0; n < 4; ++n)
          acc[m][n] = __builtin_amdgcn_mfma_f32_16x16x32_bf16(af[m], bfr[n], acc[m][n], 0, 0, 0);
    }
    __syncthreads();
  }

  #pragma unroll
  for (int m = 0; m < 4; ++m) {
    int grow0 = t0 + wm * 64 + m * 16 + lhi * 4;   // C/D: row=(lane>>4)*4+r, col=lane&15
    #pragma unroll
    for (int n = 0; n < 4; ++n) {
      int gcol = n0 + wn * 64 + n * 16 + llo;
      float bb = bias[gcol];
      #pragma unroll
      for (int r = 0; r < 4; ++r) {
        int grow = grow0 + r;
        float v = acc[m][n][r] + bb;
        if (EPI == 0) {
          v = fmaxf(v, 0.f);
          ((unsigned short*)outp)[(size_t)grow * NDIM + gcol] = f2b(v);
        } else if (EPI == 1) {
          ((float*)outp)[(size_t)grow * NDIM + gcol] = v;
        } else {
          int l = grow & (L_ - 1), b = grow >> 11;
          if (l != LM_)
            ((float*)outp)[((size_t)(l * B_ + b)) * H2_ + gcol] = v;
        }
      }
    }
  }
}

// ---------------------------------------------------------------- LN
__global__ __launch_bounds__(256) void ln_kernel(
    const float* __restrict__ X, const int* __restrict__ seq,
    const float* __restrict__ embed, const float* __restrict__ gam,
    const float* __restrict__ bet, unsigned short* __restrict__ Hbf,
    float* __restrict__ Hlast)
{
  int t = blockIdx.x * 4 + (threadIdx.x >> 6);
  int lane = threadIdx.x & 63;
  const float* xr = X + (size_t)t * H_;
  const float* er = embed + (size_t)seq[t] * H_;
  float4 x0 = *(const float4*)(xr + lane * 8);
  float4 x1 = *(const float4*)(xr + lane * 8 + 4);
  float4 e0 = *(const float4*)(er + lane * 8);
  float4 e1 = *(const float4*)(er + lane * 8 + 4);
  float xs[8] = {x0.x + e0.x, x0.y + e0.y, x0.z + e0.z, x0.w + e0.w,
                 x1.x + e1.x, x1.y + e1.y, x1.z + e1.z, x1.w + e1.w};
  float sum = 0.f, sq = 0.f;
  #pragma unroll
  for (int j = 0; j < 8; ++j) { sum += xs[j]; sq = fmaf(xs[j], xs[j], sq); }
  #pragma unroll
  for (int m = 1; m < 64; m <<= 1) { sum += __shfl_xor(sum, m); sq += __shfl_xor(sq, m); }
  float mu = sum * (1.f / H_);
  float var = sq * (1.f / H_) - mu * mu;
  float rs = rsqrtf(var + 1e-5f);
  float4 g0 = *(const float4*)(gam + lane * 8);
  float4 g1 = *(const float4*)(gam + lane * 8 + 4);
  float4 b0 = *(const float4*)(bet + lane * 8);
  float4 b1 = *(const float4*)(bet + lane * 8 + 4);
  float gs[8] = {g0.x, g0.y, g0.z, g0.w, g1.x, g1.y, g1.z, g1.w};
  float bs[8] = {b0.x, b0.y, b0.z, b0.w, b1.x, b1.y, b1.z, b1.w};
  float h[8];
  #pragma unroll
  for (int j = 0; j < 8; ++j) h[j] = (xs[j] - mu) * rs * gs[j] + bs[j];
  uint4 o;
  o.x = (unsigned)f2b(h[0]) | ((unsigned)f2b(h[1]) << 16);
  o.y = (unsigned)f2b(h[2]) | ((unsigned)f2b(h[3]) << 16);
  o.z = (unsigned)f2b(h[4]) | ((unsigned)f2b(h[5]) << 16);
  o.w = (unsigned)f2b(h[6]) | ((unsigned)f2b(h[7]) << 16);
  *(uint4*)(Hbf + (size_t)t * H_ + lane * 8) = o;
  if ((t & (L_ - 1)) == LM_) {
    int bi = t >> 11;
    #pragma unroll
    for (int j = 0; j < 8; ++j) Hlast[bi * H_ + lane * 8 + j] = h[j];
  }
}

// ---------------------------------------------------------------- q projection (fp32, exact path)
__global__ __launch_bounds__(64) void qproj_kernel(
    const float* __restrict__ Hlast, const float* __restrict__ wq,
    const float* __restrict__ bq, float* __restrict__ qbuf)
{
  int b = blockIdx.x >> 3, n = blockIdx.x & 7;
  int d = threadIdx.x;
  float acc = bq[n * 64 + d];
  const float* w = wq + (size_t)n * H_ * HH_ + d;
  const float* h = Hlast + b * H_;
  for (int k = 0; k < H_; ++k) acc = fmaf(h[k], w[(size_t)k * HH_], acc);
  qbuf[b * H_ + n * 64 + d] = acc;
}

// ---------------------------------------------------------------- rn precompute
// rn2[(b*8+n)*2048 + l] = 1/(||k_{l,b,n}||^2 + 1e-6)  (layout: contiguous in l
// so the scan's per-batch row is coalesced / s_load-able)
__global__ __launch_bounds__(256) void rnk_kernel(
    const float* __restrict__ KV, float* __restrict__ rn2)
{
  int w = blockIdx.x * 4 + (threadIdx.x >> 6);
  if (w >= LM_ * B_) return;                 // 32752 waves: one per (l,b)
  int lane = threadIdx.x & 63;
  int l = w >> 4, b = w & 15;
  const float* p = KV + (size_t)(l * B_ + b) * H2_ + lane * 8;
  float4 a = *(const float4*)p;
  float4 c = *(const float4*)(p + 4);
  float s = a.x*a.x + a.y*a.y + a.z*a.z + a.w*a.w
          + c.x*c.x + c.y*c.y + c.z*c.z + c.w*c.w;
  s = dpp_add<0xB1>(s); s = dpp_add<0x4E>(s); s = dpp_add<0x141>(s);
  if ((lane & 7) == 0)
    rn2[((size_t)b * 8 + (lane >> 3)) * 2048 + l] = 1.0f / (s + 1e-6f);
}

// ---------------------------------------------------------------- scan (delta rule), fp32
// 256 blocks (b,n,rowhalf) x 4 waves. Wave w: rows [half*32+8w, +8).
// Lane (r=lane>>3, cg=lane&7): row i = half*32+8w+r, cols cg*8..cg*8+8.
// KV rows staged 32-steps-at-a-time into double-buffered LDS via
// global_load_lds (issue next batch BEFORE computing current -> HBM latency
// hidden under ~1.6Kcy of compute; __syncthreads drains vmcnt per batch).
__device__ inline void dstep(float (&M)[8], const float* kvb, const float* rnrow,
                             int s, int cg, int iglob) {
  float4 ka = *(const float4*)(kvb + s * 128 + cg * 8);
  float4 kb = *(const float4*)(kvb + s * 128 + cg * 8 + 4);
  float vi = kvb[s * 128 + 64 + iglob];
  float rr = rnrow[s];                       // wave-uniform -> s_load
  float pa = M[0] * ka.x;
  pa = fmaf(M[1], ka.y, pa); pa = fmaf(M[2], ka.z, pa); pa = fmaf(M[3], ka.w, pa);
  float pb = M[4] * kb.x;
  pb = fmaf(M[5], kb.y, pb); pb = fmaf(M[6], kb.z, pb); pb = fmaf(M[7], kb.w, pb);
  float p = pa + pb;
  p = dpp_add<0xB1>(p); p = dpp_add<0x4E>(p); p = dpp_add<0x141>(p);
  float d = fmaf(-p, rr, vi);
  M[0] = fmaf(d, ka.x, M[0]); M[1] = fmaf(d, ka.y, M[1]);
  M[2] = fmaf(d, ka.z, M[2]); M[3] = fmaf(d, ka.w, M[3]);
  M[4] = fmaf(d, kb.x, M[4]); M[5] = fmaf(d, kb.y, M[5]);
  M[6] = fmaf(d, kb.z, M[6]); M[7] = fmaf(d, kb.w, M[7]);
}

__global__ __launch_bounds__(256) void scan_kernel(
    const float* __restrict__ KV, const float* __restrict__ rn2,
    const float* __restrict__ qbuf, float* __restrict__ ctx)
{
  __shared__ float kv[2][SB_ * 128];         // 2 x 16 KB double buffer
  const int bid = blockIdx.x;
  const int pair = bid >> 1, half = bid & 1;
  const int b = pair >> 3, n = pair & 7;
  const int tid = threadIdx.x;
  const int w = tid >> 6, lane = tid & 63;
  const int r = lane >> 3, cg = lane & 7;
  const int iglob = half * 32 + w * 8 + r;

  // staging: wave w stages 1KB chunks 4w..4w+3; chunk j covers batch steps
  // 8w+2j + (lane>>5); lane sources f32 col (lane&31)*4 of the 128-f32 row
  // (k at +0, v at row+512 -> +448 after col>=64).
  const int col4 = (lane & 31) * 4;
  const int goffc = (col4 < 64) ? col4 : (col4 + 448);
  const float* gsrc = KV + (size_t)(8 * w + (lane >> 5)) * 16384
                         + (size_t)b * 1024 + n * 64 + goffc;
  const float* rnbp = rn2 + (size_t)(b * 8 + n) * 2048;

  float M[8];
  #pragma unroll
  for (int c = 0; c < 8; ++c) M[c] = 0.f;

  // prologue: stage batch 0
  #pragma unroll
  for (int j = 0; j < 4; ++j)
    gload_lds16(gsrc + j * 32768, &kv[0][(4 * w + j) * 256]);
  gsrc += 524288;                            // -> batch 1
  __syncthreads();

  for (int bt = 0; bt < NBATCH_; ++bt) {
    const int cur = bt & 1;
    if (bt + 1 < NBATCH_) {
      // phantom step 2047 (batch 63, step 31) clamped per-lane back to row
      // 2046: stays within memory already touched; value never consumed.
      int adj = (bt + 1 == NBATCH_ - 1 && w == 3 && (lane >> 5)) ? 16384 : 0;
      gload_lds16(gsrc + 0 * 32768,       &kv[cur ^ 1][(4 * w + 0) * 256]);
      gload_lds16(gsrc + 1 * 32768,       &kv[cur ^ 1][(4 * w + 1) * 256]);
      gload_lds16(gsrc + 2 * 32768,       &kv[cur ^ 1][(4 * w + 2) * 256]);
      gload_lds16(gsrc + 3 * 32768 - adj, &kv[cur ^ 1][(4 * w + 3) * 256]);
      gsrc += 524288;
    }
    const float* kvb = &kv[cur][0];
    const float* rnrow = rnbp + bt * SB_;
    if (bt < NBATCH_ - 1) {
      #pragma unroll
      for (int s = 0; s < SB_; ++s) dstep(M, kvb, rnrow, s, cg, iglob);
    } else {
      #pragma unroll
      for (int s = 0; s < SB_ - 1; ++s) dstep(M, kvb, rnrow, s, cg, iglob);
    }
    __syncthreads();
  }

  // ctx[b][n*64+i] = sum_j M[i][j] q[j]
  const float* qp = qbuf + b * H_ + n * 64 + cg * 8;
  float4 qa = *(const float4*)(qp);
  float4 qb = *(const float4*)(qp + 4);
  float p = M[0] * qa.x;
  p = fmaf(M[1], qa.y, p); p = fmaf(M[2], qa.z, p); p = fmaf(M[3], qa.w, p);
  p = fmaf(M[4], qb.x, p); p = fmaf(M[5], qb.y, p);
  p = fmaf(M[6], qb.z, p); p = fmaf(M[7], qb.w, p);
  p = dpp_add<0xB1>(p); p = dpp_add<0x4E>(p); p = dpp_add<0x141>(p);
  if (cg == 0) ctx[b * H_ + n * 64 + iglob] = p;
}

// ---------------------------------------------------------------- output projections (fp32)
__global__ __launch_bounds__(256) void opproj_kernel(
    const float* __restrict__ ctx, const float* __restrict__ wop,
    const float* __restrict__ bop, float* __restrict__ o1t)
{
  int id = blockIdx.x * 256 + threadIdx.x;   // 8192
  int b = id >> 9, h = id & 511;
  float acc = bop[h];
  const float* c = ctx + b * H_;
  for (int k = 0; k < H_; ++k) acc = fmaf(c[k], wop[(size_t)k * H_ + h], acc);
  o1t[h * B_ + b] = acc;                     // [h][b] for vectorized reads downstream
}

__global__ __launch_bounds__(256) void outproj_kernel(
    const float* __restrict__ o1t, const float* __restrict__ wout,
    const float* __restrict__ bout, float* __restrict__ out)
{
  __shared__ float o1s[H_ * B_];             // 32 KiB
  for (int idx = threadIdx.x; idx < H_ * B_; idx += 256) o1s[idx] = o1t[idx];
  __syncthreads();
  int v = blockIdx.x * 256 + threadIdx.x;    // 125 blocks * 256 = 32000 exactly
  float bo = bout[v];
  float acc[B_];
  #pragma unroll
  for (int b = 0; b < B_; ++b) acc[b] = bo;
  for (int h = 0; h < H_; ++h) {
    float w = wout[(size_t)h * V_ + v];
    const float4* op = (const float4*)&o1s[h * B_];
    float4 a0 = op[0], a1 = op[1], a2 = op[2], a3 = op[3];
    float oa[16] = {a0.x,a0.y,a0.z,a0.w, a1.x,a1.y,a1.z,a1.w,
                    a2.x,a2.y,a2.z,a2.w, a3.x,a3.y,a3.z,a3.w};
    #pragma unroll
    for (int b = 0; b < B_; ++b) acc[b] = fmaf(oa[b], w, acc[b]);
  }
  #pragma unroll
  for (int b = 0; b < B_; ++b) out[(size_t)b * V_ + v] = acc[b];
}

// ---------------------------------------------------------------- launch
extern "C" void kernel_launch(void* const* d_in, const int* in_sizes, int n_in,
                              void* d_out, int out_size, void* d_ws, size_t ws_size,
                              hipStream_t stream)
{
  const int*   seq   = (const int*)d_in[0];
  const float* embed = (const float*)d_in[1];
  const float* ffw1  = (const float*)d_in[2];
  const float* ffb1  = (const float*)d_in[3];
  const float* ffw2  = (const float*)d_in[4];
  const float* ffb2  = (const float*)d_in[5];
  const float* lng   = (const float*)d_in[6];
  const float* lnb   = (const float*)d_in[7];
  const float* wk    = (const float*)d_in[8];
  const float* bk    = (const float*)d_in[9];
  const float* wv    = (const float*)d_in[10];
  const float* bv    = (const float*)d_in[11];
  const float* wq    = (const float*)d_in[12];
  const float* bq    = (const float*)d_in[13];
  const float* wop   = (const float*)d_in[14];
  const float* bop   = (const float*)d_in[15];
  const float* wout  = (const float*)d_in[16];
  const float* bout  = (const float*)d_in[17];

  char* ws = (char*)d_ws;
  const size_t MB = 1024 * 1024;
  unsigned short* W1T   = (unsigned short*)(ws + 0 * MB);   // 1 MB
  unsigned short* W2T   = (unsigned short*)(ws + 1 * MB);   // 1 MB
  unsigned short* WkvT  = (unsigned short*)(ws + 2 * MB);   // 1 MB
  float*          bkv   = (float*)(ws + 3 * MB);            // 4 KB
  float*          Hlast = (float*)(ws + 3 * MB + 8192);     // 32 KB
  float*          qbuf  = (float*)(ws + 3 * MB + 8192 + 32768);
  float*          ctx   = (float*)(ws + 3 * MB + 8192 + 2 * 32768);
  float*          o1t   = (float*)(ws + 3 * MB + 8192 + 3 * 32768);
  unsigned short* E     = (unsigned short*)(ws + 4 * MB);   // 32 MB  [4,36)
  unsigned short* Hbf   = E;                                // reuses E after FFN consumes it
  float*          rn2   = (float*)(ws + 4 * MB);            // 1 MB; reuses Hbf region (dead after kv-gemm)
  unsigned short* Hmid  = (unsigned short*)(ws + 36 * MB);  // 64 MB  [36,100)
  float*          X     = (float*)(ws + 100 * MB);          // 64 MB  [100,164)
  float*          KV    = (float*)(ws + 36 * MB);           // ~134 MB [36,~170) reuses Hmid+X after LN

  prep_kernel  <<<dim3(2048), dim3(256), 0, stream>>>(ffw1, ffw2, wk, wv, bk, bv, W1T, W2T, WkvT, bkv);
  gather_kernel<<<dim3(8192), dim3(256), 0, stream>>>(seq, embed, E);
  gemm_bt<512, 1024, 0><<<dim3(256, 8), dim3(256), 0, stream>>>(E, W1T, ffb1, Hmid);
  gemm_bt<1024, 512, 1><<<dim3(256, 4), dim3(256), 0, stream>>>(Hmid, W2T, ffb2, X);
  ln_kernel    <<<dim3(8192), dim3(256), 0, stream>>>(X, seq, embed, lng, lnb, Hbf, Hlast);
  gemm_bt<512, 1024, 2><<<dim3(256, 8), dim3(256), 0, stream>>>(Hbf, WkvT, bkv, KV);
  rnk_kernel   <<<dim3(8188), dim3(256), 0, stream>>>(KV, rn2);
  qproj_kernel <<<dim3(128), dim3(64), 0, stream>>>(Hlast, wq, bq, qbuf);
  scan_kernel  <<<dim3(256), dim3(256), 0, stream>>>(KV, rn2, qbuf, ctx);
  opproj_kernel<<<dim3(32), dim3(256), 0, stream>>>(ctx, wop, bop, o1t);
  outproj_kernel<<<dim3(125), dim3(256), 0, stream>>>(o1t, wout, bout, (float*)d_out);
}

// Round 9
// 660.981 us; speedup vs baseline: 2.2109x; 1.0630x over previous
//
#include <hip/hip_runtime.h>
#include <hip/hip_bf16.h>

#define B_   16
#define L_   2048
#define H_   512
#define NH_  8
#define HH_  64
#define V_   32000
#define T_   32768
#define H2_  1024
#define LM_  2047   // L-1
#define RD_  16     // backward-scan prefetch ring depth

typedef __attribute__((ext_vector_type(8))) short  short8;
typedef __attribute__((ext_vector_type(4))) float  floatx4;

__device__ inline unsigned short f2b(float x) {
  __hip_bfloat16 h = __float2bfloat16(x);
  return *reinterpret_cast<unsigned short*>(&h);
}

// DPP sum stages (pure VALU): 0xB1 xor1, 0x4E xor2, 0x141 row_half_mirror,
// 0x140 row_mirror, 0x142 row_bcast15, 0x143 row_bcast31 (all gfx9-classic).
template<int CTRL>
__device__ inline float dpp_add(float x) {
  union { float f; int i; } u, r;
  u.f = x;
  r.i = __builtin_amdgcn_update_dpp(u.i, u.i, CTRL, 0xF, 0xF, false);
  return x + r.f;
}

// Canonical gfx9 wave64 reduction -> total in lanes 48-63 -> readlane 63
// broadcasts via SGPR. No permlane/inline-asm (R8's suspect path removed).
__device__ inline float wave_total(float x) {
  x = dpp_add<0xB1>(x);    // pair sums
  x = dpp_add<0x4E>(x);    // quad sums
  x = dpp_add<0x141>(x);   // 8-sums
  x = dpp_add<0x140>(x);   // 16-sums (each row)
  x = dpp_add<0x142>(x);   // bcast15: lanes16-31=r0+r1, lanes48-63=r2+r3
  x = dpp_add<0x143>(x);   // bcast31: lanes48-63 = total
  union { float f; int i; } u;
  u.f = x;
  u.i = __builtin_amdgcn_readlane(u.i, 63);
  return u.f;
}

// ---------------------------------------------------------------- prep
__global__ __launch_bounds__(256) void prep_kernel(
    const float* __restrict__ w1, const float* __restrict__ w2,
    const float* __restrict__ wk, const float* __restrict__ wv,
    const float* __restrict__ bk, const float* __restrict__ bv,
    unsigned short* __restrict__ W1T, unsigned short* __restrict__ W2T,
    unsigned short* __restrict__ WkvT, float* __restrict__ bkv)
{
  int id = blockIdx.x * 256 + threadIdx.x;   // 524288 threads
  { int n = id >> 9, k = id & 511;
    W1T[id] = f2b(w1[(size_t)k * H2_ + n]); }
  { int n = id >> 10, k = id & 1023;
    W2T[id] = f2b(w2[(size_t)k * H_ + n]); }
  { int j = id >> 9, h = id & 511;
    float val;
    if (j < 512) val = wk[((size_t)(j >> 6) * H_ + h) * HH_ + (j & 63)];
    else { int jj = j - 512; val = wv[((size_t)(jj >> 6) * H_ + h) * HH_ + (jj & 63)]; }
    WkvT[id] = f2b(val); }
  if (id < 1024) bkv[id] = (id < 512) ? bk[id] : bv[id - 512];
}

// ---------------------------------------------------------------- gather
__global__ __launch_bounds__(256) void gather_kernel(
    const int* __restrict__ seq, const float* __restrict__ embed,
    unsigned short* __restrict__ E)
{
  int t = blockIdx.x * 4 + (threadIdx.x >> 6);
  int lane = threadIdx.x & 63;
  const float* er = embed + (size_t)seq[t] * H_;
  float4 a = *(const float4*)(er + lane * 8);
  float4 b = *(const float4*)(er + lane * 8 + 4);
  uint4 o;
  o.x = (unsigned)f2b(a.x) | ((unsigned)f2b(a.y) << 16);
  o.y = (unsigned)f2b(a.z) | ((unsigned)f2b(a.w) << 16);
  o.z = (unsigned)f2b(b.x) | ((unsigned)f2b(b.y) << 16);
  o.w = (unsigned)f2b(b.z) | ((unsigned)f2b(b.w) << 16);
  *(uint4*)(E + (size_t)t * H_ + lane * 8) = o;
}

// ---------------------------------------------------------------- GEMM
// C[M][N] = A[M][K] @ BT[N][K]^T + bias, 128x128 tile, BK=64, 4 waves.
template<int KDIM, int NDIM, int EPI>
__global__ __launch_bounds__(256) void gemm_bt(
    const unsigned short* __restrict__ A, const unsigned short* __restrict__ BT,
    const float* __restrict__ bias, void* __restrict__ outp)
{
  __shared__ uint4 smv[2048];                 // 32 KiB: As 16K + Bs 16K
  char* As = (char*)smv;
  char* Bs = As + 16384;
  const int tid = threadIdx.x;
  const int t0 = blockIdx.x * 128;
  const int n0 = blockIdx.y * 128;
  const int wid = tid >> 6, lane = tid & 63;
  const int wm = wid >> 1, wn = wid & 1;
  const int lhi = lane >> 4, llo = lane & 15;

  floatx4 acc[4][4];
  #pragma unroll
  for (int m = 0; m < 4; ++m)
    #pragma unroll
    for (int n = 0; n < 4; ++n)
      acc[m][n] = (floatx4){0.f, 0.f, 0.f, 0.f};

  for (int k0 = 0; k0 < KDIM; k0 += 64) {
    #pragma unroll
    for (int i = 0; i < 4; ++i) {            // stage 128x64 bf16 for A and B
      int idx = tid + i * 256;               // 0..1023 16B-chunks
      int row = idx >> 3, c = idx & 7;
      uint4 va = *(const uint4*)(A  + (size_t)(t0 + row) * KDIM + k0 + c * 8);
      uint4 vb = *(const uint4*)(BT + (size_t)(n0 + row) * KDIM + k0 + c * 8);
      int off = row * 128 + ((c * 16) ^ ((row & 7) << 4));   // XOR swizzle (G4)
      *(uint4*)(As + off) = va;
      *(uint4*)(Bs + off) = vb;
    }
    __syncthreads();
    #pragma unroll
    for (int kk = 0; kk < 2; ++kk) {
      short8 af[4], bfr[4];
      #pragma unroll
      for (int s = 0; s < 4; ++s) {
        int arow = wm * 64 + s * 16 + llo;
        af[s]  = *(const short8*)(As + arow * 128 + ((kk * 64 + lhi * 16) ^ ((arow & 7) << 4)));
        int brow = wn * 64 + s * 16 + llo;
        bfr[s] = *(const short8*)(Bs + brow * 128 + ((kk * 64 + lhi * 16) ^ ((brow & 7) << 4)));
      }
      #pragma unroll
      for (int m = 0; m < 4; ++m)
        #pragma unroll
        for (int n = 0; n < 4; ++n)
          acc[m][n] = __builtin_amdgcn_mfma_f32_16x16x32_bf16(af[m], bfr[n], acc[m][n], 0, 0, 0);
    }
    __syncthreads();
  }

  #pragma unroll
  for (int m = 0; m < 4; ++m) {
    int grow0 = t0 + wm * 64 + m * 16 + lhi * 4;   // C/D: row=(lane>>4)*4+r, col=lane&15
    #pragma unroll
    for (int n = 0; n < 4; ++n) {
      int gcol = n0 + wn * 64 + n * 16 + llo;
      float bb = bias[gcol];
      #pragma unroll
      for (int r = 0; r < 4; ++r) {
        int grow = grow0 + r;
        float v = acc[m][n][r] + bb;
        if (EPI == 0) {
          v = fmaxf(v, 0.f);
          ((unsigned short*)outp)[(size_t)grow * NDIM + gcol] = f2b(v);
        } else if (EPI == 1) {
          ((float*)outp)[(size_t)grow * NDIM + gcol] = v;
        } else {
          int l = grow & (L_ - 1), b = grow >> 11;
          if (l != LM_)
            ((float*)outp)[((size_t)(l * B_ + b)) * H2_ + gcol] = v;
        }
      }
    }
  }
}

// ---------------------------------------------------------------- LN
__global__ __launch_bounds__(256) void ln_kernel(
    const float* __restrict__ X, const int* __restrict__ seq,
    const float* __restrict__ embed, const float* __restrict__ gam,
    const float* __restrict__ bet, unsigned short* __restrict__ Hbf,
    float* __restrict__ Hlast)
{
  int t = blockIdx.x * 4 + (threadIdx.x >> 6);
  int lane = threadIdx.x & 63;
  const float* xr = X + (size_t)t * H_;
  const float* er = embed + (size_t)seq[t] * H_;
  float4 x0 = *(const float4*)(xr + lane * 8);
  float4 x1 = *(const float4*)(xr + lane * 8 + 4);
  float4 e0 = *(const float4*)(er + lane * 8);
  float4 e1 = *(const float4*)(er + lane * 8 + 4);
  float xs[8] = {x0.x + e0.x, x0.y + e0.y, x0.z + e0.z, x0.w + e0.w,
                 x1.x + e1.x, x1.y + e1.y, x1.z + e1.z, x1.w + e1.w};
  float sum = 0.f, sq = 0.f;
  #pragma unroll
  for (int j = 0; j < 8; ++j) { sum += xs[j]; sq = fmaf(xs[j], xs[j], sq); }
  #pragma unroll
  for (int m = 1; m < 64; m <<= 1) { sum += __shfl_xor(sum, m); sq += __shfl_xor(sq, m); }
  float mu = sum * (1.f / H_);
  float var = sq * (1.f / H_) - mu * mu;
  float rs = rsqrtf(var + 1e-5f);
  float4 g0 = *(const float4*)(gam + lane * 8);
  float4 g1 = *(const float4*)(gam + lane * 8 + 4);
  float4 b0 = *(const float4*)(bet + lane * 8);
  float4 b1 = *(const float4*)(bet + lane * 8 + 4);
  float gs[8] = {g0.x, g0.y, g0.z, g0.w, g1.x, g1.y, g1.z, g1.w};
  float bs[8] = {b0.x, b0.y, b0.z, b0.w, b1.x, b1.y, b1.z, b1.w};
  float h[8];
  #pragma unroll
  for (int j = 0; j < 8; ++j) h[j] = (xs[j] - mu) * rs * gs[j] + bs[j];
  uint4 o;
  o.x = (unsigned)f2b(h[0]) | ((unsigned)f2b(h[1]) << 16);
  o.y = (unsigned)f2b(h[2]) | ((unsigned)f2b(h[3]) << 16);
  o.z = (unsigned)f2b(h[4]) | ((unsigned)f2b(h[5]) << 16);
  o.w = (unsigned)f2b(h[6]) | ((unsigned)f2b(h[7]) << 16);
  *(uint4*)(Hbf + (size_t)t * H_ + lane * 8) = o;
  if ((t & (L_ - 1)) == LM_) {
    int bi = t >> 11;
    #pragma unroll
    for (int j = 0; j < 8; ++j) Hlast[bi * H_ + lane * 8 + j] = h[j];
  }
}

// ---------------------------------------------------------------- q projection (fp32, exact path)
__global__ __launch_bounds__(64) void qproj_kernel(
    const float* __restrict__ Hlast, const float* __restrict__ wq,
    const float* __restrict__ bq, float* __restrict__ qbuf)
{
  int b = blockIdx.x >> 3, n = blockIdx.x & 7;
  int d = threadIdx.x;
  float acc = bq[n * 64 + d];
  const float* w = wq + (size_t)n * H_ * HH_ + d;
  const float* h = Hlast + b * H_;
  for (int k = 0; k < H_; ++k) acc = fmaf(h[k], w[(size_t)k * HH_], acc);
  qbuf[b * H_ + n * 64 + d] = acc;
}

// ---------------------------------------------------------------- rn precompute
// rn2[(b*8+n)*2048 + l] = 1/(||k_{l,b,n}||^2 + 1e-6)
__global__ __launch_bounds__(256) void rnk_kernel(
    const float* __restrict__ KV, float* __restrict__ rn2)
{
  int w = blockIdx.x * 4 + (threadIdx.x >> 6);
  if (w >= LM_ * B_) return;                 // 32752 waves: one per (l,b)
  int lane = threadIdx.x & 63;
  int l = w >> 4, b = w & 15;
  const float* p = KV + (size_t)(l * B_ + b) * H2_ + lane * 8;
  float4 a = *(const float4*)p;
  float4 c = *(const float4*)(p + 4);
  float s = a.x*a.x + a.y*a.y + a.z*a.z + a.w*a.w
          + c.x*c.x + c.y*c.y + c.z*c.z + c.w*c.w;
  s = dpp_add<0xB1>(s); s = dpp_add<0x4E>(s); s = dpp_add<0x141>(s);
  if ((lane & 7) == 0)
    rn2[((size_t)b * 8 + (lane >> 3)) * 2048 + l] = 1.0f / (s + 1e-6f);
}

// ---------------------------------------------------------------- backward scan
// ctx = M_T q with M never formed: A_t = I - k_t k_t^T/nu_t (symmetric),
//   z_{T+1} = q;  s_t = k_t . z_{t+1};  z_t = z_{t+1} - (s_t/nu_t) k_t;
//   ctx = sum_t v_t s_t   (t descending 2046..0).
// 128 blocks (one wave per (b,n) pair), lane = element index. Per step the
// wave loads k_t[lane], v_t[lane] (256B each, coalesced) via a RD_-deep
// statically-indexed register ring. Serial chain: mul + 6 DPP adds +
// readlane + mul + 2 fma ~= 65cy.
__global__ __launch_bounds__(64, 1) void scanb_kernel(
    const float* __restrict__ KV, const float* __restrict__ rn2,
    const float* __restrict__ qbuf, float* __restrict__ ctx)
{
  const int pair = blockIdx.x;               // b*8+n
  const int lane = threadIdx.x;
  const int b = pair >> 3, n = pair & 7;
  const float* kbase = KV + (size_t)b * H2_ + n * 64 + lane;  // + l*16384
  const float* vbase = kbase + 512;
  const float* rnp = rn2 + (size_t)pair * 2048;

  float z = qbuf[pair * 64 + lane];
  float cx = 0.f;

  float kk[RD_], vv[RD_], rr[RD_];
  #pragma unroll
  for (int j = 0; j < RD_; ++j) {
    int l = 2046 - j;
    kk[j] = kbase[(size_t)l * (B_ * H2_)];
    vv[j] = vbase[(size_t)l * (B_ * H2_)];
    rr[j] = rnp[l];
  }

  // main: 127 iters x 16 steps -> t = 2046 .. 15
  for (int it = 0; it < 127; ++it) {
    int tbase = 2046 - it * RD_;
    #pragma unroll
    for (int j = 0; j < RD_; ++j) {
      int t = tbase - j;
      float s = wave_total(kk[j] * z);
      float c = s * rr[j];
      z  = fmaf(-c, kk[j], z);
      cx = fmaf(s,  vv[j], cx);
      int lnx = t - RD_;
      if (lnx < 0) lnx = 0;                  // slot 15's final load unused
      kk[j] = kbase[(size_t)lnx * (B_ * H2_)];
      vv[j] = vbase[(size_t)lnx * (B_ * H2_)];
      rr[j] = rnp[lnx];
    }
  }
  // tail: t = 14..0 live in slots 0..14
  #pragma unroll
  for (int j = 0; j < 15; ++j) {
    float s = wave_total(kk[j] * z);
    float c = s * rr[j];
    z  = fmaf(-c, kk[j], z);
    cx = fmaf(s,  vv[j], cx);
  }

  ctx[pair * 64 + lane] = cx;
}

// ---------------------------------------------------------------- output projections (fp32)
__global__ __launch_bounds__(256) void opproj_kernel(
    const float* __restrict__ ctx, const float* __restrict__ wop,
    const float* __restrict__ bop, float* __restrict__ o1t)
{
  int id = blockIdx.x * 256 + threadIdx.x;   // 8192
  int b = id >> 9, h = id & 511;
  float acc = bop[h];
  const float* c = ctx + b * H_;
  for (int k = 0; k < H_; ++k) acc = fmaf(c[k], wop[(size_t)k * H_ + h], acc);
  o1t[h * B_ + b] = acc;                     // [h][b] for vectorized reads downstream
}

__global__ __launch_bounds__(256) void outproj_kernel(
    const float* __restrict__ o1t, const float* __restrict__ wout,
    const float* __restrict__ bout, float* __restrict__ out)
{
  __shared__ float o1s[H_ * B_];             // 32 KiB
  for (int idx = threadIdx.x; idx < H_ * B_; idx += 256) o1s[idx] = o1t[idx];
  __syncthreads();
  int v = blockIdx.x * 256 + threadIdx.x;    // 125 blocks * 256 = 32000 exactly
  float bo = bout[v];
  float acc[B_];
  #pragma unroll
  for (int b = 0; b < B_; ++b) acc[b] = bo;
  for (int h = 0; h < H_; ++h) {
    float w = wout[(size_t)h * V_ + v];
    const float4* op = (const float4*)&o1s[h * B_];
    float4 a0 = op[0], a1 = op[1], a2 = op[2], a3 = op[3];
    float oa[16] = {a0.x,a0.y,a0.z,a0.w, a1.x,a1.y,a1.z,a1.w,
                    a2.x,a2.y,a2.z,a2.w, a3.x,a3.y,a3.z,a3.w};
    #pragma unroll
    for (int b = 0; b < B_; ++b) acc[b] = fmaf(oa[b], w, acc[b]);
  }
  #pragma unroll
  for (int b = 0; b < B_; ++b) out[(size_t)b * V_ + v] = acc[b];
}

// ---------------------------------------------------------------- launch
extern "C" void kernel_launch(void* const* d_in, const int* in_sizes, int n_in,
                              void* d_out, int out_size, void* d_ws, size_t ws_size,
                              hipStream_t stream)
{
  const int*   seq   = (const int*)d_in[0];
  const float* embed = (const float*)d_in[1];
  const float* ffw1  = (const float*)d_in[2];
  const float* ffb1  = (const float*)d_in[3];
  const float* ffw2  = (const float*)d_in[4];
  const float* ffb2  = (const float*)d_in[5];
  const float* lng   = (const float*)d_in[6];
  const float* lnb   = (const float*)d_in[7];
  const float* wk    = (const float*)d_in[8];
  const float* bk    = (const float*)d_in[9];
  const float* wv    = (const float*)d_in[10];
  const float* bv    = (const float*)d_in[11];
  const float* wq    = (const float*)d_in[12];
  const float* bq    = (const float*)d_in[13];
  const float* wop   = (const float*)d_in[14];
  const float* bop   = (const float*)d_in[15];
  const float* wout  = (const float*)d_in[16];
  const float* bout  = (const float*)d_in[17];

  char* ws = (char*)d_ws;
  const size_t MB = 1024 * 1024;
  unsigned short* W1T   = (unsigned short*)(ws + 0 * MB);   // 1 MB
  unsigned short* W2T   = (unsigned short*)(ws + 1 * MB);   // 1 MB
  unsigned short* WkvT  = (unsigned short*)(ws + 2 * MB);   // 1 MB
  float*          bkv   = (float*)(ws + 3 * MB);            // 4 KB
  float*          Hlast = (float*)(ws + 3 * MB + 8192);     // 32 KB
  float*          qbuf  = (float*)(ws + 3 * MB + 8192 + 32768);
  float*          ctx   = (float*)(ws + 3 * MB + 8192 + 2 * 32768);
  float*          o1t   = (float*)(ws + 3 * MB + 8192 + 3 * 32768);
  unsigned short* E     = (unsigned short*)(ws + 4 * MB);   // 32 MB  [4,36)
  unsigned short* Hbf   = E;                                // reuses E after FFN consumes it
  float*          rn2   = (float*)(ws + 4 * MB);            // 1 MB; reuses Hbf region (dead after kv-gemm)
  unsigned short* Hmid  = (unsigned short*)(ws + 36 * MB);  // 64 MB  [36,100)
  float*          X     = (float*)(ws + 100 * MB);          // 64 MB  [100,164)
  float*          KV    = (float*)(ws + 36 * MB);           // ~134 MB [36,~170) reuses Hmid+X after LN

  prep_kernel  <<<dim3(2048), dim3(256), 0, stream>>>(ffw1, ffw2, wk, wv, bk, bv, W1T, W2T, WkvT, bkv);
  gather_kernel<<<dim3(8192), dim3(256), 0, stream>>>(seq, embed, E);
  gemm_bt<512, 1024, 0><<<dim3(256, 8), dim3(256), 0, stream>>>(E, W1T, ffb1, Hmid);
  gemm_bt<1024, 512, 1><<<dim3(256, 4), dim3(256), 0, stream>>>(Hmid, W2T, ffb2, X);
  ln_kernel    <<<dim3(8192), dim3(256), 0, stream>>>(X, seq, embed, lng, lnb, Hbf, Hlast);
  gemm_bt<512, 1024, 2><<<dim3(256, 8), dim3(256), 0, stream>>>(Hbf, WkvT, bkv, KV);
  rnk_kernel   <<<dim3(8188), dim3(256), 0, stream>>>(KV, rn2);
  qproj_kernel <<<dim3(128), dim3(64), 0, stream>>>(Hlast, wq, bq, qbuf);
  scanb_kernel <<<dim3(128), dim3(64), 0, stream>>>(KV, rn2, qbuf, ctx);
  opproj_kernel<<<dim3(32), dim3(256), 0, stream>>>(ctx, wop, bop, o1t);
  outproj_kernel<<<dim3(125), dim3(256), 0, stream>>>(o1t, wout, bout, (float*)d_out);
}